// Round 14
// baseline (217.030 us; speedup 1.0000x reference)
//
#include <hip/hip_runtime.h>

constexpr int NN = 50000;   // nodes
constexpr int NE = 500000;  // edges
constexpr int NB = 32;      // graphs
constexpr int NTROWS = 256; // B * TASKS_PER
constexpr int SCB = 196;    // ceil(NN/256) scan blocks
constexpr int NBLK64 = (NN + 63) / 64;  // 782 row-tiles of 64

typedef __attribute__((ext_vector_type(8))) short bf16x8;
typedef __attribute__((ext_vector_type(4))) float f32x4;

static __device__ __forceinline__ unsigned short f2bf(float f) {
  unsigned u = __float_as_uint(f);
  unsigned r = (u + 0x7FFFu + ((u >> 16) & 1u)) >> 16;  // RNE
  return (unsigned short)r;
}
static __device__ __forceinline__ float bf2f(unsigned short s) {
  return __uint_as_float(((unsigned)s) << 16);
}

// ---------------- weight prep: 10x 128x128 + embW 64x128 -> bf16 [n][k]; also zero cnt ----------------
__global__ void k_wprep(const float* __restrict__ msgW, const float* __restrict__ updW,
                        const float* __restrict__ resW, const float* __restrict__ embW,
                        unsigned short* __restrict__ wbf, int* __restrict__ cnt) {
  int idx = blockIdx.x * 256 + threadIdx.x;  // 10*16384 + 8192 = 172032 = 672*256
  if (idx < NN) cnt[idx] = 0;
  if (idx >= 10 * 16384 + 8192) return;
  if (idx < 10 * 16384) {
    int m = idx >> 14, e = idx & 16383;
    int nn = e >> 7, kk = e & 127;
    int l = m / 5, t = m % 5;
    const float* src;
    if (t == 0)      src = msgW + (size_t)l * 257 * 128;
    else if (t == 1) src = msgW + (size_t)l * 257 * 128 + 128 * 128;
    else if (t == 2) src = updW + (size_t)l * 256 * 128;
    else if (t == 3) src = updW + (size_t)l * 256 * 128 + 128 * 128;
    else             src = resW + (size_t)l * 128 * 128;
    wbf[idx] = f2bf(src[kk * 128 + nn]);
  } else {
    int e = idx - 10 * 16384;          // embW^T: [128 n][64 k]
    int nn = e >> 6, kk = e & 63;
    wbf[idx] = f2bf(embW[kk * 128 + nn]);
  }
}

// ---------------- CSR histogram + graph starts (merged) ----------------
__global__ void k_count_gstart(const int* __restrict__ col, int* __restrict__ cnt,
                               const int* __restrict__ batch, int* __restrict__ gstart) {
  int e = blockIdx.x * 256 + threadIdx.x;
  if (e < NE) atomicAdd(&cnt[col[e]], 1);
  if (e < NN) {
    int b = batch[e];
    if (e == 0) gstart[b] = 0;
    else if (batch[e - 1] != b) gstart[b] = e;
    if (e == NN - 1) gstart[b + 1] = NN;
  }
}

// ---------------- hierarchical exclusive scan ----------------
__global__ __launch_bounds__(256) void k_scan1(const int* __restrict__ cnt,
                                               int* __restrict__ starts,
                                               int* __restrict__ bsum) {
  __shared__ int s[256];
  int t = threadIdx.x;
  int i = blockIdx.x * 256 + t;
  int v = (i < NN) ? cnt[i] : 0;
  s[t] = v; __syncthreads();
  for (int off = 1; off < 256; off <<= 1) {
    int u = (t >= off) ? s[t - off] : 0;
    __syncthreads();
    s[t] += u;
    __syncthreads();
  }
  if (i < NN) starts[i] = s[t] - v;
  if (t == 255) bsum[blockIdx.x] = s[255];
}

__global__ __launch_bounds__(256) void k_scan2(int* __restrict__ bsum) {
  __shared__ int s[256];
  int t = threadIdx.x;
  int v = (t < SCB) ? bsum[t] : 0;
  s[t] = v; __syncthreads();
  for (int off = 1; off < 256; off <<= 1) {
    int u = (t >= off) ? s[t - off] : 0;
    __syncthreads();
    s[t] += u;
    __syncthreads();
  }
  if (t < SCB) bsum[t] = s[t] - v;
}

__global__ __launch_bounds__(256) void k_scan3(int* __restrict__ starts,
                                               const int* __restrict__ bsum,
                                               int* __restrict__ cursor) {
  int i = blockIdx.x * 256 + threadIdx.x;
  if (i < NN) {
    int v = starts[i] + bsum[blockIdx.x];
    starts[i] = v;
    cursor[i] = v;
  }
  if (i == 0) starts[NN] = NE;
}

// ---------------- scatter edges into CSR order; (row, dist) packed as int2 ----------------
__global__ void k_scatter(const int* __restrict__ row, const int* __restrict__ col,
                          const float* __restrict__ x,
                          int* __restrict__ cursor, int2* __restrict__ spack) {
  int e = blockIdx.x * blockDim.x + threadIdx.x;
  if (e >= NE) return;
  int r = row[e], c = col[e];
  float dx = x[3*r+0] - x[3*c+0];
  float dy = x[3*r+1] - x[3*c+1];
  float dz = x[3*r+2] - x[3*c+2];
  float d = dx*dx + dy*dy + dz*dz;
  int pos = atomicAdd(&cursor[c], 1);
  spack[pos] = make_int2(r, __float_as_int(d));
}

// ---------------- staging: bf16 64-row tile -> swizzled LDS (pure copy) ----------------
template<int TPB>
static __device__ __forceinline__ void stage_tile64(
    unsigned short* lds, const unsigned short* __restrict__ src, int row0, int n, int tid) {
  #pragma unroll
  for (int ch = tid; ch < 1024; ch += TPB) {    // 64 rows * 16 chunks of 16B
    int r = ch >> 4, kc = ch & 15;
    bf16x8 v = {0,0,0,0,0,0,0,0};
    if (row0 + r < n) v = *(const bf16x8*)(src + (size_t)(row0 + r) * 128 + kc * 8);
    int byte = (r * 256 + kc * 16) ^ ((r & 7) << 4);
    *(bf16x8*)((char*)lds + byte) = v;
  }
}

// ---------------- vector store: swizzled 64-row LDS tile -> global row-major bf16 ----------------
template<int TPB>
static __device__ __forceinline__ void vstore_tile64(
    unsigned short* __restrict__ dst, const unsigned short* lds, int row0, int n, int tid) {
  #pragma unroll
  for (int ch = tid; ch < 1024; ch += TPB) {
    int r = ch >> 4, kc = ch & 15;
    if (row0 + r < n) {
      bf16x8 v = *(const bf16x8*)((const char*)lds + ((r * 256 + kc * 16) ^ ((r & 7) << 4)));
      *(bf16x8*)(dst + (size_t)(row0 + r) * 128 + kc * 8) = v;
    }
  }
}

// ---------------- epilogue: C-frags (f32, 4 row-tiles x 1 col-tile) -> swizzled LDS ----------------
static __device__ __forceinline__ void epi_to_lds64(
    unsigned short* lds, const f32x4 (&acc)[4], int lane, int c0) {
  int ccol = lane & 15, crow4 = (lane >> 4) * 4;
  int cc = c0 + ccol;
  #pragma unroll
  for (int rt = 0; rt < 4; ++rt)
    #pragma unroll
    for (int j = 0; j < 4; ++j) {
      int lrow = rt * 16 + crow4 + j;
      int lbyte = (lrow * 256 + cc * 2) ^ ((lrow & 7) << 4);
      *(unsigned short*)((char*)lds + lbyte) = f2bf(acc[rt][j]);
    }
}

// ---------------- in-kernel pull: dual-node interleaved gather into swizzled LDS ----------------
// 16 lanes per node (each lane owns 8 cols); each thread handles nodes lr and lr+32
// with their edge loops interleaved for memory-level parallelism.
static __device__ __forceinline__ void gather_aggr_lds(
    unsigned short* As, const int* __restrict__ starts, const int2* __restrict__ spack,
    const unsigned short* __restrict__ A, const unsigned short* __restrict__ Bm,
    const float* __restrict__ wd, const float* __restrict__ mb,
    int row0, int n, int tid) {
  int c0 = (tid & 15) * 8;
  float4 w0 = *(const float4*)(wd + c0), w1 = *(const float4*)(wd + c0 + 4);
  float4 bb0 = *(const float4*)(mb + c0), bb1 = *(const float4*)(mb + c0 + 4);
  float wv[8] = {w0.x, w0.y, w0.z, w0.w, w1.x, w1.y, w1.z, w1.w};
  float bv[8] = {bb0.x, bb0.y, bb0.z, bb0.w, bb1.x, bb1.y, bb1.z, bb1.w};
  int lrA = tid >> 4, lrB = lrA + 32;
  int nodeA = row0 + lrA, nodeB = row0 + lrB;
  bool vA = nodeA < n, vB = nodeB < n;
  float baseA[8], baseB[8], accA[8], accB[8];
  #pragma unroll
  for (int j = 0; j < 8; ++j) { accA[j] = 0.f; accB[j] = 0.f; baseA[j] = 0.f; baseB[j] = 0.f; }
  int iA = 0, eA = 0, iB = 0, eB = 0;
  if (vA) {
    union { bf16x8 v; unsigned short s[8]; } ub;
    ub.v = *(const bf16x8*)(Bm + (size_t)nodeA * 128 + c0);
    #pragma unroll
    for (int j = 0; j < 8; ++j) baseA[j] = bf2f(ub.s[j]) + bv[j];
    iA = starts[nodeA]; eA = starts[nodeA + 1];
  }
  if (vB) {
    union { bf16x8 v; unsigned short s[8]; } ub;
    ub.v = *(const bf16x8*)(Bm + (size_t)nodeB * 128 + c0);
    #pragma unroll
    for (int j = 0; j < 8; ++j) baseB[j] = bf2f(ub.s[j]) + bv[j];
    iB = starts[nodeB]; eB = starts[nodeB + 1];
  }
  // interleaved main loop: 2 edges of A + 2 edges of B in flight together
  while (iA + 2 <= eA && iB + 2 <= eB) {
    int2 pa0 = spack[iA + 0], pa1 = spack[iA + 1];
    int2 pb0 = spack[iB + 0], pb1 = spack[iB + 1];
    union { bf16x8 v; unsigned short s[8]; } a0, a1, b0, b1;
    a0.v = *(const bf16x8*)(A + (size_t)pa0.x * 128 + c0);
    a1.v = *(const bf16x8*)(A + (size_t)pa1.x * 128 + c0);
    b0.v = *(const bf16x8*)(A + (size_t)pb0.x * 128 + c0);
    b1.v = *(const bf16x8*)(A + (size_t)pb1.x * 128 + c0);
    float da0 = __int_as_float(pa0.y), da1 = __int_as_float(pa1.y);
    float db0 = __int_as_float(pb0.y), db1 = __int_as_float(pb1.y);
    #pragma unroll
    for (int j = 0; j < 8; ++j) {
      accA[j] += fmaxf(bf2f(a0.s[j]) + fmaf(da0, wv[j], baseA[j]), 0.f);
      accA[j] += fmaxf(bf2f(a1.s[j]) + fmaf(da1, wv[j], baseA[j]), 0.f);
      accB[j] += fmaxf(bf2f(b0.s[j]) + fmaf(db0, wv[j], baseB[j]), 0.f);
      accB[j] += fmaxf(bf2f(b1.s[j]) + fmaf(db1, wv[j], baseB[j]), 0.f);
    }
    iA += 2; iB += 2;
  }
  // tail A (4x unroll + scalar)
  for (; iA + 4 <= eA; iA += 4) {
    int2 p0 = spack[iA + 0], p1 = spack[iA + 1];
    int2 p2 = spack[iA + 2], p3 = spack[iA + 3];
    union { bf16x8 v; unsigned short s[8]; } a0, a1, a2, a3;
    a0.v = *(const bf16x8*)(A + (size_t)p0.x * 128 + c0);
    a1.v = *(const bf16x8*)(A + (size_t)p1.x * 128 + c0);
    a2.v = *(const bf16x8*)(A + (size_t)p2.x * 128 + c0);
    a3.v = *(const bf16x8*)(A + (size_t)p3.x * 128 + c0);
    float d0 = __int_as_float(p0.y), d1 = __int_as_float(p1.y);
    float d2 = __int_as_float(p2.y), d3 = __int_as_float(p3.y);
    #pragma unroll
    for (int j = 0; j < 8; ++j) {
      accA[j] += fmaxf(bf2f(a0.s[j]) + fmaf(d0, wv[j], baseA[j]), 0.f);
      accA[j] += fmaxf(bf2f(a1.s[j]) + fmaf(d1, wv[j], baseA[j]), 0.f);
      accA[j] += fmaxf(bf2f(a2.s[j]) + fmaf(d2, wv[j], baseA[j]), 0.f);
      accA[j] += fmaxf(bf2f(a3.s[j]) + fmaf(d3, wv[j], baseA[j]), 0.f);
    }
  }
  for (; iA < eA; ++iA) {
    int2 p = spack[iA];
    union { bf16x8 v; unsigned short s[8]; } a;
    a.v = *(const bf16x8*)(A + (size_t)p.x * 128 + c0);
    float d = __int_as_float(p.y);
    #pragma unroll
    for (int j = 0; j < 8; ++j)
      accA[j] += fmaxf(bf2f(a.s[j]) + fmaf(d, wv[j], baseA[j]), 0.f);
  }
  // tail B (4x unroll + scalar)
  for (; iB + 4 <= eB; iB += 4) {
    int2 p0 = spack[iB + 0], p1 = spack[iB + 1];
    int2 p2 = spack[iB + 2], p3 = spack[iB + 3];
    union { bf16x8 v; unsigned short s[8]; } a0, a1, a2, a3;
    a0.v = *(const bf16x8*)(A + (size_t)p0.x * 128 + c0);
    a1.v = *(const bf16x8*)(A + (size_t)p1.x * 128 + c0);
    a2.v = *(const bf16x8*)(A + (size_t)p2.x * 128 + c0);
    a3.v = *(const bf16x8*)(A + (size_t)p3.x * 128 + c0);
    float d0 = __int_as_float(p0.y), d1 = __int_as_float(p1.y);
    float d2 = __int_as_float(p2.y), d3 = __int_as_float(p3.y);
    #pragma unroll
    for (int j = 0; j < 8; ++j) {
      accB[j] += fmaxf(bf2f(a0.s[j]) + fmaf(d0, wv[j], baseB[j]), 0.f);
      accB[j] += fmaxf(bf2f(a1.s[j]) + fmaf(d1, wv[j], baseB[j]), 0.f);
      accB[j] += fmaxf(bf2f(a2.s[j]) + fmaf(d2, wv[j], baseB[j]), 0.f);
      accB[j] += fmaxf(bf2f(a3.s[j]) + fmaf(d3, wv[j], baseB[j]), 0.f);
    }
  }
  for (; iB < eB; ++iB) {
    int2 p = spack[iB];
    union { bf16x8 v; unsigned short s[8]; } a;
    a.v = *(const bf16x8*)(A + (size_t)p.x * 128 + c0);
    float d = __int_as_float(p.y);
    #pragma unroll
    for (int j = 0; j < 8; ++j)
      accB[j] += fmaxf(bf2f(a.s[j]) + fmaf(d, wv[j], baseB[j]), 0.f);
  }
  // write both nodes' results to swizzled LDS (zeros for invalid nodes)
  union { bf16x8 v; unsigned short s[8]; } oA, oB;
  #pragma unroll
  for (int j = 0; j < 8; ++j) {
    oA.s[j] = vA ? f2bf(accA[j]) : (unsigned short)0;
    oB.s[j] = vB ? f2bf(accB[j]) : (unsigned short)0;
  }
  int byteA = (lrA * 256 + (tid & 15) * 16) ^ ((lrA & 7) << 4);
  int byteB = (lrB * 256 + (tid & 15) * 16) ^ ((lrB & 7) << 4);
  *(bf16x8*)((char*)As + byteA) = oA.v;
  *(bf16x8*)((char*)As + byteB) = oB.v;
}

// ---------------- fused embed (K=64 MFMA) + dual msg GEMM, 2-tile LDS (32 KB) ----------------
__global__ __launch_bounds__(512) void k_embed_dual(
    const float* __restrict__ h, const unsigned short* __restrict__ embWt,
    const float* __restrict__ embB,
    const unsigned short* __restrict__ W1t, const unsigned short* __restrict__ W2t,
    unsigned short* __restrict__ emb, unsigned short* __restrict__ Y1,
    unsigned short* __restrict__ Y2, int n) {
  __shared__ unsigned short T0[64 * 128];   // h-tile (Hs layout), later Y1/Y2 staging
  __shared__ unsigned short T1[64 * 128];   // X tile
  int row0 = blockIdx.x * 64;
  int tid = threadIdx.x;
  int wave = tid >> 6, lane = tid & 63;
  int c0 = wave * 16;                       // each wave owns 16 cols
  int arow = lane & 15, kb = (lane >> 4) * 8;
  {  // stage h tile fp32 -> bf16 into T0 (Hs layout: row stride 128 B)
    int r = tid >> 3, kc = tid & 7;
    union { bf16x8 v; unsigned short s[8]; } u;
    if (row0 + r < n) {
      const float* p = h + (size_t)(row0 + r) * 64 + kc * 8;
      float4 f0 = *(const float4*)p, f1 = *(const float4*)(p + 4);
      u.s[0]=f2bf(f0.x); u.s[1]=f2bf(f0.y); u.s[2]=f2bf(f0.z); u.s[3]=f2bf(f0.w);
      u.s[4]=f2bf(f1.x); u.s[5]=f2bf(f1.y); u.s[6]=f2bf(f1.z); u.s[7]=f2bf(f1.w);
    } else {
      #pragma unroll
      for (int j = 0; j < 8; ++j) u.s[j] = 0;
    }
    int byte = (r * 128 + kc * 16) ^ ((r & 7) << 4);
    *(bf16x8*)((char*)T0 + byte) = u.v;
  }
  float bB = embB[c0 + (lane & 15)];
  __syncthreads();
  // P1: embed MFMA (K=64) from T0 -> X into T1 (scalar, +bias)
  f32x4 accE[4] = {};
  #pragma unroll
  for (int ks = 0; ks < 2; ++ks) {
    bf16x8 b = *(const bf16x8*)(embWt + (size_t)(c0 + arow) * 64 + ks * 32 + kb);
    #pragma unroll
    for (int rt = 0; rt < 4; ++rt) {
      int r = rt * 16 + arow;
      int byte = (r * 128 + (ks * 32 + kb) * 2) ^ ((r & 7) << 4);
      bf16x8 a = *(const bf16x8*)((const char*)T0 + byte);
      accE[rt] = __builtin_amdgcn_mfma_f32_16x16x32_bf16(a, b, accE[rt], 0, 0, 0);
    }
  }
  {
    int ccol = lane & 15, crow4 = (lane >> 4) * 4;
    int cc = c0 + ccol;
    #pragma unroll
    for (int rt = 0; rt < 4; ++rt)
      #pragma unroll
      for (int j = 0; j < 4; ++j) {
        int lrow = rt * 16 + crow4 + j;
        int lbyte = (lrow * 256 + cc * 2) ^ ((lrow & 7) << 4);
        *(unsigned short*)((char*)T1 + lbyte) = f2bf(accE[rt][j] + bB);
      }
  }
  __syncthreads();   // T0 reads done; T1 (X) complete
  // P2: dual GEMM from T1; vstore emb; stage acc1 into T0 (dead)
  f32x4 acc1[4] = {};
  f32x4 acc2[4] = {};
  #pragma unroll
  for (int ks = 0; ks < 4; ++ks) {
    int k0 = ks * 32;
    bf16x8 b1 = *(const bf16x8*)(W1t + (size_t)(c0 + arow) * 128 + k0 + kb);
    bf16x8 b2 = *(const bf16x8*)(W2t + (size_t)(c0 + arow) * 128 + k0 + kb);
    #pragma unroll
    for (int rt = 0; rt < 4; ++rt) {
      int r = rt * 16 + arow;
      int byte = (r * 256 + (k0 + kb) * 2) ^ ((r & 7) << 4);
      bf16x8 a = *(const bf16x8*)((const char*)T1 + byte);
      acc1[rt] = __builtin_amdgcn_mfma_f32_16x16x32_bf16(a, b1, acc1[rt], 0, 0, 0);
      acc2[rt] = __builtin_amdgcn_mfma_f32_16x16x32_bf16(a, b2, acc2[rt], 0, 0, 0);
    }
  }
  vstore_tile64<512>(emb, T1, row0, n, tid);
  epi_to_lds64(T0, acc1, lane, c0);
  __syncthreads();
  vstore_tile64<512>(Y1, T0, row0, n, tid);
  __syncthreads();
  epi_to_lds64(T0, acc2, lane, c0);
  __syncthreads();
  vstore_tile64<512>(Y2, T0, row0, n, tid);
}

// ---------------- fused pull + node update + next-layer dual GEMM, 2-tile LDS ----------------
__global__ __launch_bounds__(512, 4) void k_node_dual_pull(
    const unsigned short* __restrict__ emb,
    const int* __restrict__ starts, const int2* __restrict__ spack,
    const unsigned short* __restrict__ Agth, const unsigned short* __restrict__ Bm,
    const float* __restrict__ wd, const float* __restrict__ mb,
    const unsigned short* __restrict__ U1t, const unsigned short* __restrict__ U2t,
    const unsigned short* __restrict__ Rt, const float* __restrict__ updb,
    const unsigned short* __restrict__ W1t, const unsigned short* __restrict__ W2t,
    unsigned short* __restrict__ out, unsigned short* __restrict__ Y1,
    unsigned short* __restrict__ Y2, int n) {
  __shared__ unsigned short T0[64 * 128];   // emb, then X
  __shared__ unsigned short T1[64 * 128];   // aggr, then Y1, then Y2
  int row0 = blockIdx.x * 64;
  int tid = threadIdx.x;
  int wave = tid >> 6, lane = tid & 63;
  int c0 = wave * 16;
  int arow = lane & 15, kb = (lane >> 4) * 8;
  stage_tile64<512>(T0, emb, row0, n, tid);
  gather_aggr_lds(T1, starts, spack, Agth, Bm, wd, mb, row0, n, tid);
  float uB = updb[c0 + (lane & 15)];
  __syncthreads();
  // P1: node update MFMAs from T0 (emb) + T1 (aggr)
  f32x4 accU[4] = {};
  f32x4 accR[4] = {};
  #pragma unroll
  for (int ks = 0; ks < 4; ++ks) {
    int k0 = ks * 32;
    bf16x8 bU1 = *(const bf16x8*)(U1t + (size_t)(c0 + arow) * 128 + k0 + kb);
    bf16x8 bU2 = *(const bf16x8*)(U2t + (size_t)(c0 + arow) * 128 + k0 + kb);
    bf16x8 bR  = *(const bf16x8*)(Rt  + (size_t)(c0 + arow) * 128 + k0 + kb);
    #pragma unroll
    for (int rt = 0; rt < 4; ++rt) {
      int r = rt * 16 + arow;
      int byte = (r * 256 + (k0 + kb) * 2) ^ ((r & 7) << 4);
      bf16x8 aE = *(const bf16x8*)((const char*)T0 + byte);
      bf16x8 aA = *(const bf16x8*)((const char*)T1 + byte);
      accU[rt] = __builtin_amdgcn_mfma_f32_16x16x32_bf16(aE, bU1, accU[rt], 0, 0, 0);
      accU[rt] = __builtin_amdgcn_mfma_f32_16x16x32_bf16(aA, bU2, accU[rt], 0, 0, 0);
      accR[rt] = __builtin_amdgcn_mfma_f32_16x16x32_bf16(aE, bR,  accR[rt], 0, 0, 0);
    }
  }
  __syncthreads();   // all T0/T1 reads done
  // epilogue: X -> T0 (in place over dead emb tile)
  {
    int ccol = lane & 15, crow4 = (lane >> 4) * 4;
    int cc = c0 + ccol;
    #pragma unroll
    for (int rt = 0; rt < 4; ++rt)
      #pragma unroll
      for (int j = 0; j < 4; ++j) {
        int lrow = rt * 16 + crow4 + j;
        int lbyte = (lrow * 256 + cc * 2) ^ ((lrow & 7) << 4);
        *(unsigned short*)((char*)T0 + lbyte) =
            f2bf(accR[rt][j] + fmaxf(accU[rt][j] + uB, 0.f));
      }
  }
  __syncthreads();   // X complete
  // P2: dual GEMM from T0 (X); vstore out; stage acc1 -> T1 (dead)
  f32x4 acc1[4] = {};
  f32x4 acc2[4] = {};
  #pragma unroll
  for (int ks = 0; ks < 4; ++ks) {
    int k0 = ks * 32;
    bf16x8 b1 = *(const bf16x8*)(W1t + (size_t)(c0 + arow) * 128 + k0 + kb);
    bf16x8 b2 = *(const bf16x8*)(W2t + (size_t)(c0 + arow) * 128 + k0 + kb);
    #pragma unroll
    for (int rt = 0; rt < 4; ++rt) {
      int r = rt * 16 + arow;
      int byte = (r * 256 + (k0 + kb) * 2) ^ ((r & 7) << 4);
      bf16x8 a = *(const bf16x8*)((const char*)T0 + byte);
      acc1[rt] = __builtin_amdgcn_mfma_f32_16x16x32_bf16(a, b1, acc1[rt], 0, 0, 0);
      acc2[rt] = __builtin_amdgcn_mfma_f32_16x16x32_bf16(a, b2, acc2[rt], 0, 0, 0);
    }
  }
  vstore_tile64<512>(out, T0, row0, n, tid);
  epi_to_lds64(T1, acc1, lane, c0);
  __syncthreads();
  vstore_tile64<512>(Y1, T1, row0, n, tid);
  __syncthreads();
  epi_to_lds64(T1, acc2, lane, c0);
  __syncthreads();
  vstore_tile64<512>(Y2, T1, row0, n, tid);
}

// ---------------- fused pull + final node update + pooling partials (shfl reduce) ----------------
__global__ __launch_bounds__(512, 4) void k_node_pool_pull(
    const unsigned short* __restrict__ emb,
    const int* __restrict__ starts, const int2* __restrict__ spack,
    const unsigned short* __restrict__ Agth, const unsigned short* __restrict__ Bm,
    const float* __restrict__ wd, const float* __restrict__ mb,
    const unsigned short* __restrict__ U1t, const unsigned short* __restrict__ U2t,
    const unsigned short* __restrict__ Rt, const float* __restrict__ updb,
    const int* __restrict__ batch,
    float* __restrict__ ppart, int* __restrict__ pgid, int n) {
  __shared__ unsigned short Es[64 * 128];
  __shared__ unsigned short As[64 * 128];
  __shared__ int sbat[64];
  int row0 = blockIdx.x * 64;
  int tid = threadIdx.x;
  int wave = tid >> 6, lane = tid & 63;
  int c0 = wave * 16;
  int arow = lane & 15, kb = (lane >> 4) * 8;
  stage_tile64<512>(Es, emb, row0, n, tid);
  if (tid < 64) sbat[tid] = batch[min(row0 + tid, n - 1)];
  gather_aggr_lds(As, starts, spack, Agth, Bm, wd, mb, row0, n, tid);
  float uB = updb[c0 + (lane & 15)];
  __syncthreads();
  f32x4 accU[4] = {};
  f32x4 accR[4] = {};
  #pragma unroll
  for (int ks = 0; ks < 4; ++ks) {
    int k0 = ks * 32;
    bf16x8 bU1 = *(const bf16x8*)(U1t + (size_t)(c0 + arow) * 128 + k0 + kb);
    bf16x8 bU2 = *(const bf16x8*)(U2t + (size_t)(c0 + arow) * 128 + k0 + kb);
    bf16x8 bR  = *(const bf16x8*)(Rt  + (size_t)(c0 + arow) * 128 + k0 + kb);
    #pragma unroll
    for (int rt = 0; rt < 4; ++rt) {
      int r = rt * 16 + arow;
      int byte = (r * 256 + (k0 + kb) * 2) ^ ((r & 7) << 4);
      bf16x8 aE = *(const bf16x8*)((const char*)Es + byte);
      bf16x8 aA = *(const bf16x8*)((const char*)As + byte);
      accU[rt] = __builtin_amdgcn_mfma_f32_16x16x32_bf16(aE, bU1, accU[rt], 0, 0, 0);
      accU[rt] = __builtin_amdgcn_mfma_f32_16x16x32_bf16(aA, bU2, accU[rt], 0, 0, 0);
      accR[rt] = __builtin_amdgcn_mfma_f32_16x16x32_bf16(aE, bR,  accR[rt], 0, 0, 0);
    }
  }
  // per-thread bucket sums over its 16 rows, then shfl-fold lane-groups
  int g0 = sbat[0];
  int crow4 = (lane >> 4) * 4;
  float s0 = 0.f, s1 = 0.f;
  #pragma unroll
  for (int rt = 0; rt < 4; ++rt)
    #pragma unroll
    for (int j = 0; j < 4; ++j) {
      int lrow = rt * 16 + crow4 + j;
      if (row0 + lrow < n) {
        float v = accR[rt][j] + fmaxf(accU[rt][j] + uB, 0.f);
        if (sbat[lrow] == g0) s0 += v; else s1 += v;
      }
    }
  s0 += __shfl_xor(s0, 16); s0 += __shfl_xor(s0, 32);
  s1 += __shfl_xor(s1, 16); s1 += __shfl_xor(s1, 32);
  if ((lane >> 4) == 0) {
    int cc = c0 + (lane & 15);
    ppart[(size_t)(2 * blockIdx.x) * 128 + cc] = s0;
    ppart[(size_t)(2 * blockIdx.x + 1) * 128 + cc] = s1;
  }
  if (tid == 0) {
    int gl = sbat[63];
    pgid[2 * blockIdx.x] = g0;
    pgid[2 * blockIdx.x + 1] = (gl != g0) ? gl : -1;
  }
}

// ---------------- pool reduce: per-graph sum of block partials / count ----------------
__global__ __launch_bounds__(128) void k_pool2(const float* __restrict__ ppart,
                                               const int* __restrict__ pgid,
                                               const int* __restrict__ gstart,
                                               float* __restrict__ pooled) {
  int g = blockIdx.x, t = threadIdx.x;
  int blo = gstart[g] >> 6;
  int bhi = (gstart[g + 1] - 1) >> 6;
  float acc = 0.f;
  for (int b = blo; b <= bhi; ++b) {
    if (pgid[2 * b] == g)     acc += ppart[(size_t)(2 * b) * 128 + t];
    if (pgid[2 * b + 1] == g) acc += ppart[(size_t)(2 * b + 1) * 128 + t];
  }
  float cntf = (float)(gstart[g + 1] - gstart[g]);
  pooled[g * 128 + t] = acc / fmaxf(cntf, 1.f);
}

// ---------------- task head: 4-layer MLP per (graph, task) row (fp32) ----------------
__global__ __launch_bounds__(128) void k_head(
    const float* __restrict__ pooled, const float* __restrict__ temb,
    const int* __restrict__ tasks,
    const float* __restrict__ W0, const float* __restrict__ b0,
    const float* __restrict__ W1, const float* __restrict__ b1,
    const float* __restrict__ W2, const float* __restrict__ b2,
    const float* __restrict__ W3, const float* __restrict__ b3,
    float* __restrict__ out) {
  __shared__ float f[192];
  __shared__ float za[128];
  __shared__ float zb[128];
  int rowi = blockIdx.x, t = threadIdx.x;
  int proto = tasks[rowi*2 + 0];
  int tid2  = tasks[rowi*2 + 1];
  f[t] = pooled[proto*128 + t];
  if (t < 64) f[128 + t] = temb[(size_t)tid2*64 + t];
  __syncthreads();
  float a = b0[t];
  for (int k = 0; k < 192; ++k) a += f[k] * W0[k*128 + t];
  za[t] = fmaxf(a, 0.f);
  __syncthreads();
  a = b1[t];
  for (int k = 0; k < 128; ++k) a += za[k] * W1[k*128 + t];
  zb[t] = fmaxf(a, 0.f);
  __syncthreads();
  a = b2[t];
  for (int k = 0; k < 128; ++k) a += zb[k] * W2[k*128 + t];
  za[t] = fmaxf(a, 0.f);
  __syncthreads();
  if (t < 3) {
    a = b3[t];
    for (int k = 0; k < 128; ++k) a += za[k] * W3[k*3 + t];
    out[rowi*3 + t] = a;
  }
}

extern "C" void kernel_launch(void* const* d_in, const int* in_sizes, int n_in,
                              void* d_out, int out_size, void* d_ws, size_t ws_size,
                              hipStream_t stream) {
  const float* h    = (const float*)d_in[0];
  const float* x    = (const float*)d_in[1];
  const int*   ei   = (const int*)d_in[2];
  const int*   batch= (const int*)d_in[4];
  const int*   tasks= (const int*)d_in[5];
  const float* embW = (const float*)d_in[7];
  const float* embB = (const float*)d_in[8];
  const float* resW = (const float*)d_in[9];
  const float* msgW = (const float*)d_in[10];
  const float* msgB = (const float*)d_in[11];
  const float* updW = (const float*)d_in[12];
  const float* updB = (const float*)d_in[13];
  const float* W0 = (const float*)d_in[14]; const float* b0 = (const float*)d_in[15];
  const float* W1 = (const float*)d_in[16]; const float* b1 = (const float*)d_in[17];
  const float* W2 = (const float*)d_in[18]; const float* b2 = (const float*)d_in[19];
  const float* W3 = (const float*)d_in[20]; const float* b3 = (const float*)d_in[21];
  const float* temb = (const float*)d_in[22];
  const int* row = ei;
  const int* col = ei + NE;

  // bf16 buffers first (16B alignment), then fp32, then int2/int
  unsigned short* bws = (unsigned short*)d_ws;
  unsigned short* e0   = bws;  bws += (size_t)NN*128;
  unsigned short* e1   = bws;  bws += (size_t)NN*128;
  unsigned short* A0   = bws;  bws += (size_t)NN*128;
  unsigned short* B0   = bws;  bws += (size_t)NN*128;
  unsigned short* A1   = bws;  bws += (size_t)NN*128;
  unsigned short* B1   = bws;  bws += (size_t)NN*128;
  unsigned short* wbf  = bws;  bws += 10*16384 + 8192;
  float* ws = (float*)bws;
  float* pooled= ws;  ws += NB*128;
  float* ppart = ws;  ws += (size_t)2*NBLK64*128;
  int2*  spack = (int2*)ws;
  int*   iws   = (int*)(spack + NE);
  int*   cnt    = iws;  iws += NN;
  int*   starts = iws;  iws += NN + 1;
  int*   cursor = iws;  iws += NN;
  int*   gstart = iws;  iws += NB + 1;
  int*   bsum   = iws;  iws += 256;
  int*   pgid   = iws;  iws += 2*NBLK64;

  const unsigned short* embWt = wbf + (size_t)10*16384;

  // weight prep + cnt zero
  k_wprep<<<672, 256, 0, stream>>>(msgW, updW, resW, embW, wbf, cnt);

  // CSR build (by destination col) + graph starts
  k_count_gstart<<<(NE + 255)/256, 256, 0, stream>>>(col, cnt, batch, gstart);
  k_scan1<<<SCB, 256, 0, stream>>>(cnt, starts, bsum);
  k_scan2<<<1, 256, 0, stream>>>(bsum);
  k_scan3<<<SCB, 256, 0, stream>>>(starts, bsum, cursor);
  k_scatter<<<(NE + 255)/256, 256, 0, stream>>>(row, col, x, cursor, spack);

  const unsigned short* m0W1t = wbf + (size_t)0 * 16384;
  const unsigned short* m0W2t = wbf + (size_t)1 * 16384;
  const unsigned short* u0W1t = wbf + (size_t)2 * 16384;
  const unsigned short* u0W2t = wbf + (size_t)3 * 16384;
  const unsigned short* r0Wt  = wbf + (size_t)4 * 16384;
  const unsigned short* m1W1t = wbf + (size_t)5 * 16384;
  const unsigned short* m1W2t = wbf + (size_t)6 * 16384;
  const unsigned short* u1W1t = wbf + (size_t)7 * 16384;
  const unsigned short* u1W2t = wbf + (size_t)8 * 16384;
  const unsigned short* r1Wt  = wbf + (size_t)9 * 16384;

  // embed + layer-0 dual msg GEMM
  k_embed_dual<<<NBLK64, 512, 0, stream>>>(h, embWt, embB, m0W1t, m0W2t,
                                           e0, A0, B0, NN);
  // layer 0: fused pull + node update + layer-1 dual GEMM  (A0/B0 -> e1, A1, B1)
  k_node_dual_pull<<<NBLK64, 512, 0, stream>>>(e0, starts, spack, A0, B0,
                                               msgW + 256*128, msgB,
                                               u0W1t, u0W2t, r0Wt, updB,
                                               m1W1t, m1W2t, e1, A1, B1, NN);
  // layer 1: fused pull + node update + pooling partials  (A1/B1 + e1 -> ppart)
  k_node_pool_pull<<<NBLK64, 512, 0, stream>>>(e1, starts, spack, A1, B1,
                                               msgW + (size_t)257*128 + 256*128,
                                               msgB + 128,
                                               u1W1t, u1W2t, r1Wt, updB + 128,
                                               batch, ppart, pgid, NN);
  k_pool2<<<NB, 128, 0, stream>>>(ppart, pgid, gstart, pooled);
  k_head<<<NTROWS, 128, 0, stream>>>(pooled, temb, tasks,
                                     W0, b0, W1, b1, W2, b2, W3, b3, (float*)d_out);
}

// Round 15
// 208.853 us; speedup vs baseline: 1.0392x; 1.0392x over previous
//
#include <hip/hip_runtime.h>

constexpr int NN = 50000;   // nodes
constexpr int NE = 500000;  // edges
constexpr int NB = 32;      // graphs
constexpr int NTROWS = 256; // B * TASKS_PER
constexpr int SCB = 196;    // ceil(NN/256) scan blocks
constexpr int NBLK64 = (NN + 63) / 64;  // 782 row-tiles of 64

typedef __attribute__((ext_vector_type(8))) short bf16x8;
typedef __attribute__((ext_vector_type(4))) float f32x4;

static __device__ __forceinline__ unsigned short f2bf(float f) {
  unsigned u = __float_as_uint(f);
  unsigned r = (u + 0x7FFFu + ((u >> 16) & 1u)) >> 16;  // RNE
  return (unsigned short)r;
}
static __device__ __forceinline__ float bf2f(unsigned short s) {
  return __uint_as_float(((unsigned)s) << 16);
}

// ---------------- weight prep: 10x 128x128 + embW 64x128 -> bf16 [n][k]; also zero cnt ----------------
__global__ void k_wprep(const float* __restrict__ msgW, const float* __restrict__ updW,
                        const float* __restrict__ resW, const float* __restrict__ embW,
                        unsigned short* __restrict__ wbf, int* __restrict__ cnt) {
  int idx = blockIdx.x * 256 + threadIdx.x;  // 10*16384 + 8192 = 172032 = 672*256
  if (idx < NN) cnt[idx] = 0;
  if (idx >= 10 * 16384 + 8192) return;
  if (idx < 10 * 16384) {
    int m = idx >> 14, e = idx & 16383;
    int nn = e >> 7, kk = e & 127;
    int l = m / 5, t = m % 5;
    const float* src;
    if (t == 0)      src = msgW + (size_t)l * 257 * 128;
    else if (t == 1) src = msgW + (size_t)l * 257 * 128 + 128 * 128;
    else if (t == 2) src = updW + (size_t)l * 256 * 128;
    else if (t == 3) src = updW + (size_t)l * 256 * 128 + 128 * 128;
    else             src = resW + (size_t)l * 128 * 128;
    wbf[idx] = f2bf(src[kk * 128 + nn]);
  } else {
    int e = idx - 10 * 16384;          // embW^T: [128 n][64 k]
    int nn = e >> 6, kk = e & 63;
    wbf[idx] = f2bf(embW[kk * 128 + nn]);
  }
}

// ---------------- CSR histogram + graph starts (merged) ----------------
__global__ void k_count_gstart(const int* __restrict__ col, int* __restrict__ cnt,
                               const int* __restrict__ batch, int* __restrict__ gstart) {
  int e = blockIdx.x * 256 + threadIdx.x;
  if (e < NE) atomicAdd(&cnt[col[e]], 1);
  if (e < NN) {
    int b = batch[e];
    if (e == 0) gstart[b] = 0;
    else if (batch[e - 1] != b) gstart[b] = e;
    if (e == NN - 1) gstart[b + 1] = NN;
  }
}

// ---------------- hierarchical exclusive scan ----------------
__global__ __launch_bounds__(256) void k_scan1(const int* __restrict__ cnt,
                                               int* __restrict__ starts,
                                               int* __restrict__ bsum) {
  __shared__ int s[256];
  int t = threadIdx.x;
  int i = blockIdx.x * 256 + t;
  int v = (i < NN) ? cnt[i] : 0;
  s[t] = v; __syncthreads();
  for (int off = 1; off < 256; off <<= 1) {
    int u = (t >= off) ? s[t - off] : 0;
    __syncthreads();
    s[t] += u;
    __syncthreads();
  }
  if (i < NN) starts[i] = s[t] - v;
  if (t == 255) bsum[blockIdx.x] = s[255];
}

__global__ __launch_bounds__(256) void k_scan2(int* __restrict__ bsum) {
  __shared__ int s[256];
  int t = threadIdx.x;
  int v = (t < SCB) ? bsum[t] : 0;
  s[t] = v; __syncthreads();
  for (int off = 1; off < 256; off <<= 1) {
    int u = (t >= off) ? s[t - off] : 0;
    __syncthreads();
    s[t] += u;
    __syncthreads();
  }
  if (t < SCB) bsum[t] = s[t] - v;
}

__global__ __launch_bounds__(256) void k_scan3(int* __restrict__ starts,
                                               const int* __restrict__ bsum,
                                               int* __restrict__ cursor) {
  int i = blockIdx.x * 256 + threadIdx.x;
  if (i < NN) {
    int v = starts[i] + bsum[blockIdx.x];
    starts[i] = v;
    cursor[i] = v;
  }
  if (i == 0) starts[NN] = NE;
}

// ---------------- scatter edges into CSR order; (row, dist) packed as int2 ----------------
__global__ void k_scatter(const int* __restrict__ row, const int* __restrict__ col,
                          const float* __restrict__ x,
                          int* __restrict__ cursor, int2* __restrict__ spack) {
  int e = blockIdx.x * blockDim.x + threadIdx.x;
  if (e >= NE) return;
  int r = row[e], c = col[e];
  float dx = x[3*r+0] - x[3*c+0];
  float dy = x[3*r+1] - x[3*c+1];
  float dz = x[3*r+2] - x[3*c+2];
  float d = dx*dx + dy*dy + dz*dz;
  int pos = atomicAdd(&cursor[c], 1);
  spack[pos] = make_int2(r, __float_as_int(d));
}

// ---------------- staging: bf16 64-row tile -> swizzled LDS (pure copy) ----------------
template<int TPB>
static __device__ __forceinline__ void stage_tile64(
    unsigned short* lds, const unsigned short* __restrict__ src, int row0, int n, int tid) {
  #pragma unroll
  for (int ch = tid; ch < 1024; ch += TPB) {    // 64 rows * 16 chunks of 16B
    int r = ch >> 4, kc = ch & 15;
    bf16x8 v = {0,0,0,0,0,0,0,0};
    if (row0 + r < n) v = *(const bf16x8*)(src + (size_t)(row0 + r) * 128 + kc * 8);
    int byte = (r * 256 + kc * 16) ^ ((r & 7) << 4);
    *(bf16x8*)((char*)lds + byte) = v;
  }
}

// ---------------- vector store: swizzled 64-row LDS tile -> global row-major bf16 ----------------
template<int TPB>
static __device__ __forceinline__ void vstore_tile64(
    unsigned short* __restrict__ dst, const unsigned short* lds, int row0, int n, int tid) {
  #pragma unroll
  for (int ch = tid; ch < 1024; ch += TPB) {
    int r = ch >> 4, kc = ch & 15;
    if (row0 + r < n) {
      bf16x8 v = *(const bf16x8*)((const char*)lds + ((r * 256 + kc * 16) ^ ((r & 7) << 4)));
      *(bf16x8*)(dst + (size_t)(row0 + r) * 128 + kc * 8) = v;
    }
  }
}

// ---------------- epilogue: C-frags (f32, 4 row-tiles x 1 col-tile) -> swizzled LDS ----------------
static __device__ __forceinline__ void epi_to_lds64(
    unsigned short* lds, const f32x4 (&acc)[4], int lane, int c0) {
  int ccol = lane & 15, crow4 = (lane >> 4) * 4;
  int cc = c0 + ccol;
  #pragma unroll
  for (int rt = 0; rt < 4; ++rt)
    #pragma unroll
    for (int j = 0; j < 4; ++j) {
      int lrow = rt * 16 + crow4 + j;
      int lbyte = (lrow * 256 + cc * 2) ^ ((lrow & 7) << 4);
      *(unsigned short*)((char*)lds + lbyte) = f2bf(acc[rt][j]);
    }
}

// ---------------- in-kernel pull: single-pass gather, 8 lanes/node ----------------
// Each thread owns ONE node (lr = tid>>3) and 16 cols (two 8-col chunks at
// kc and kc+8, i.e. cols c0..c0+7 and c0+64..c0+71). One serial edge loop.
static __device__ __forceinline__ void gather_aggr_lds(
    unsigned short* As, const int* __restrict__ starts, const int2* __restrict__ spack,
    const unsigned short* __restrict__ A, const unsigned short* __restrict__ Bm,
    const float* __restrict__ wd, const float* __restrict__ mb,
    int row0, int n, int tid) {
  int kc = tid & 7;
  int c0 = kc * 8, c1 = c0 + 64;
  int lr = tid >> 3;                 // 0..63, one node per thread
  int node = row0 + lr;
  float wv[16], bvv[16], basev[16], accv[16];
  {
    float4 wa0 = *(const float4*)(wd + c0), wa1 = *(const float4*)(wd + c0 + 4);
    float4 wb0 = *(const float4*)(wd + c1), wb1 = *(const float4*)(wd + c1 + 4);
    float4 ba0 = *(const float4*)(mb + c0), ba1 = *(const float4*)(mb + c0 + 4);
    float4 bb0 = *(const float4*)(mb + c1), bb1 = *(const float4*)(mb + c1 + 4);
    wv[0]=wa0.x; wv[1]=wa0.y; wv[2]=wa0.z; wv[3]=wa0.w;
    wv[4]=wa1.x; wv[5]=wa1.y; wv[6]=wa1.z; wv[7]=wa1.w;
    wv[8]=wb0.x; wv[9]=wb0.y; wv[10]=wb0.z; wv[11]=wb0.w;
    wv[12]=wb1.x; wv[13]=wb1.y; wv[14]=wb1.z; wv[15]=wb1.w;
    bvv[0]=ba0.x; bvv[1]=ba0.y; bvv[2]=ba0.z; bvv[3]=ba0.w;
    bvv[4]=ba1.x; bvv[5]=ba1.y; bvv[6]=ba1.z; bvv[7]=ba1.w;
    bvv[8]=bb0.x; bvv[9]=bb0.y; bvv[10]=bb0.z; bvv[11]=bb0.w;
    bvv[12]=bb1.x; bvv[13]=bb1.y; bvv[14]=bb1.z; bvv[15]=bb1.w;
  }
  union { bf16x8 v; unsigned short s[8]; } o0, o1;
  if (node < n) {
    union { bf16x8 v; unsigned short s[8]; } u0, u1;
    u0.v = *(const bf16x8*)(Bm + (size_t)node * 128 + c0);
    u1.v = *(const bf16x8*)(Bm + (size_t)node * 128 + c1);
    #pragma unroll
    for (int j = 0; j < 8; ++j) {
      basev[j]     = bf2f(u0.s[j]) + bvv[j];
      basev[j + 8] = bf2f(u1.s[j]) + bvv[j + 8];
      accv[j] = 0.f; accv[j + 8] = 0.f;
    }
    int i = starts[node], e = starts[node + 1];
    for (; i + 4 <= e; i += 4) {
      int2 p0 = spack[i + 0], p1 = spack[i + 1];
      int2 p2 = spack[i + 2], p3 = spack[i + 3];
      union { bf16x8 v; unsigned short s[8]; } a00, a01, a10, a11, a20, a21, a30, a31;
      a00.v = *(const bf16x8*)(A + (size_t)p0.x * 128 + c0);
      a01.v = *(const bf16x8*)(A + (size_t)p0.x * 128 + c1);
      a10.v = *(const bf16x8*)(A + (size_t)p1.x * 128 + c0);
      a11.v = *(const bf16x8*)(A + (size_t)p1.x * 128 + c1);
      a20.v = *(const bf16x8*)(A + (size_t)p2.x * 128 + c0);
      a21.v = *(const bf16x8*)(A + (size_t)p2.x * 128 + c1);
      a30.v = *(const bf16x8*)(A + (size_t)p3.x * 128 + c0);
      a31.v = *(const bf16x8*)(A + (size_t)p3.x * 128 + c1);
      float d0 = __int_as_float(p0.y), d1 = __int_as_float(p1.y);
      float d2 = __int_as_float(p2.y), d3 = __int_as_float(p3.y);
      #pragma unroll
      for (int j = 0; j < 8; ++j) {
        accv[j]     += fmaxf(bf2f(a00.s[j]) + fmaf(d0, wv[j],     basev[j]),     0.f);
        accv[j + 8] += fmaxf(bf2f(a01.s[j]) + fmaf(d0, wv[j + 8], basev[j + 8]), 0.f);
        accv[j]     += fmaxf(bf2f(a10.s[j]) + fmaf(d1, wv[j],     basev[j]),     0.f);
        accv[j + 8] += fmaxf(bf2f(a11.s[j]) + fmaf(d1, wv[j + 8], basev[j + 8]), 0.f);
        accv[j]     += fmaxf(bf2f(a20.s[j]) + fmaf(d2, wv[j],     basev[j]),     0.f);
        accv[j + 8] += fmaxf(bf2f(a21.s[j]) + fmaf(d2, wv[j + 8], basev[j + 8]), 0.f);
        accv[j]     += fmaxf(bf2f(a30.s[j]) + fmaf(d3, wv[j],     basev[j]),     0.f);
        accv[j + 8] += fmaxf(bf2f(a31.s[j]) + fmaf(d3, wv[j + 8], basev[j + 8]), 0.f);
      }
    }
    for (; i < e; ++i) {
      int2 p = spack[i];
      union { bf16x8 v; unsigned short s[8]; } a0, a1;
      a0.v = *(const bf16x8*)(A + (size_t)p.x * 128 + c0);
      a1.v = *(const bf16x8*)(A + (size_t)p.x * 128 + c1);
      float d = __int_as_float(p.y);
      #pragma unroll
      for (int j = 0; j < 8; ++j) {
        accv[j]     += fmaxf(bf2f(a0.s[j]) + fmaf(d, wv[j],     basev[j]),     0.f);
        accv[j + 8] += fmaxf(bf2f(a1.s[j]) + fmaf(d, wv[j + 8], basev[j + 8]), 0.f);
      }
    }
    #pragma unroll
    for (int j = 0; j < 8; ++j) {
      o0.s[j] = f2bf(accv[j]);
      o1.s[j] = f2bf(accv[j + 8]);
    }
  } else {
    #pragma unroll
    for (int j = 0; j < 8; ++j) { o0.s[j] = 0; o1.s[j] = 0; }
  }
  int byte0 = (lr * 256 + kc * 16) ^ ((lr & 7) << 4);
  int byte1 = (lr * 256 + (kc + 8) * 16) ^ ((lr & 7) << 4);
  *(bf16x8*)((char*)As + byte0) = o0.v;
  *(bf16x8*)((char*)As + byte1) = o1.v;
}

// ---------------- fused embed (K=64 MFMA) + dual msg GEMM, 2-tile LDS (32 KB) ----------------
__global__ __launch_bounds__(512) void k_embed_dual(
    const float* __restrict__ h, const unsigned short* __restrict__ embWt,
    const float* __restrict__ embB,
    const unsigned short* __restrict__ W1t, const unsigned short* __restrict__ W2t,
    unsigned short* __restrict__ emb, unsigned short* __restrict__ Y1,
    unsigned short* __restrict__ Y2, int n) {
  __shared__ unsigned short T0[64 * 128];   // h-tile (Hs layout), later Y1/Y2 staging
  __shared__ unsigned short T1[64 * 128];   // X tile
  int row0 = blockIdx.x * 64;
  int tid = threadIdx.x;
  int wave = tid >> 6, lane = tid & 63;
  int c0 = wave * 16;                       // each wave owns 16 cols
  int arow = lane & 15, kb = (lane >> 4) * 8;
  {  // stage h tile fp32 -> bf16 into T0 (Hs layout: row stride 128 B)
    int r = tid >> 3, kc = tid & 7;
    union { bf16x8 v; unsigned short s[8]; } u;
    if (row0 + r < n) {
      const float* p = h + (size_t)(row0 + r) * 64 + kc * 8;
      float4 f0 = *(const float4*)p, f1 = *(const float4*)(p + 4);
      u.s[0]=f2bf(f0.x); u.s[1]=f2bf(f0.y); u.s[2]=f2bf(f0.z); u.s[3]=f2bf(f0.w);
      u.s[4]=f2bf(f1.x); u.s[5]=f2bf(f1.y); u.s[6]=f2bf(f1.z); u.s[7]=f2bf(f1.w);
    } else {
      #pragma unroll
      for (int j = 0; j < 8; ++j) u.s[j] = 0;
    }
    int byte = (r * 128 + kc * 16) ^ ((r & 7) << 4);
    *(bf16x8*)((char*)T0 + byte) = u.v;
  }
  float bB = embB[c0 + (lane & 15)];
  __syncthreads();
  // P1: embed MFMA (K=64) from T0 -> X into T1 (scalar, +bias)
  f32x4 accE[4] = {};
  #pragma unroll
  for (int ks = 0; ks < 2; ++ks) {
    bf16x8 b = *(const bf16x8*)(embWt + (size_t)(c0 + arow) * 64 + ks * 32 + kb);
    #pragma unroll
    for (int rt = 0; rt < 4; ++rt) {
      int r = rt * 16 + arow;
      int byte = (r * 128 + (ks * 32 + kb) * 2) ^ ((r & 7) << 4);
      bf16x8 a = *(const bf16x8*)((const char*)T0 + byte);
      accE[rt] = __builtin_amdgcn_mfma_f32_16x16x32_bf16(a, b, accE[rt], 0, 0, 0);
    }
  }
  {
    int ccol = lane & 15, crow4 = (lane >> 4) * 4;
    int cc = c0 + ccol;
    #pragma unroll
    for (int rt = 0; rt < 4; ++rt)
      #pragma unroll
      for (int j = 0; j < 4; ++j) {
        int lrow = rt * 16 + crow4 + j;
        int lbyte = (lrow * 256 + cc * 2) ^ ((lrow & 7) << 4);
        *(unsigned short*)((char*)T1 + lbyte) = f2bf(accE[rt][j] + bB);
      }
  }
  __syncthreads();   // T0 reads done; T1 (X) complete
  // P2: dual GEMM from T1; vstore emb; stage acc1 into T0 (dead)
  f32x4 acc1[4] = {};
  f32x4 acc2[4] = {};
  #pragma unroll
  for (int ks = 0; ks < 4; ++ks) {
    int k0 = ks * 32;
    bf16x8 b1 = *(const bf16x8*)(W1t + (size_t)(c0 + arow) * 128 + k0 + kb);
    bf16x8 b2 = *(const bf16x8*)(W2t + (size_t)(c0 + arow) * 128 + k0 + kb);
    #pragma unroll
    for (int rt = 0; rt < 4; ++rt) {
      int r = rt * 16 + arow;
      int byte = (r * 256 + (k0 + kb) * 2) ^ ((r & 7) << 4);
      bf16x8 a = *(const bf16x8*)((const char*)T1 + byte);
      acc1[rt] = __builtin_amdgcn_mfma_f32_16x16x32_bf16(a, b1, acc1[rt], 0, 0, 0);
      acc2[rt] = __builtin_amdgcn_mfma_f32_16x16x32_bf16(a, b2, acc2[rt], 0, 0, 0);
    }
  }
  vstore_tile64<512>(emb, T1, row0, n, tid);
  epi_to_lds64(T0, acc1, lane, c0);
  __syncthreads();
  vstore_tile64<512>(Y1, T0, row0, n, tid);
  __syncthreads();
  epi_to_lds64(T0, acc2, lane, c0);
  __syncthreads();
  vstore_tile64<512>(Y2, T0, row0, n, tid);
}

// ---------------- fused pull + node update + next-layer dual GEMM, 2-tile LDS ----------------
__global__ __launch_bounds__(512, 4) void k_node_dual_pull(
    const unsigned short* __restrict__ emb,
    const int* __restrict__ starts, const int2* __restrict__ spack,
    const unsigned short* __restrict__ Agth, const unsigned short* __restrict__ Bm,
    const float* __restrict__ wd, const float* __restrict__ mb,
    const unsigned short* __restrict__ U1t, const unsigned short* __restrict__ U2t,
    const unsigned short* __restrict__ Rt, const float* __restrict__ updb,
    const unsigned short* __restrict__ W1t, const unsigned short* __restrict__ W2t,
    unsigned short* __restrict__ out, unsigned short* __restrict__ Y1,
    unsigned short* __restrict__ Y2, int n) {
  __shared__ unsigned short T0[64 * 128];   // emb, then X
  __shared__ unsigned short T1[64 * 128];   // aggr, then Y1, then Y2
  int row0 = blockIdx.x * 64;
  int tid = threadIdx.x;
  int wave = tid >> 6, lane = tid & 63;
  int c0 = wave * 16;
  int arow = lane & 15, kb = (lane >> 4) * 8;
  stage_tile64<512>(T0, emb, row0, n, tid);
  gather_aggr_lds(T1, starts, spack, Agth, Bm, wd, mb, row0, n, tid);
  float uB = updb[c0 + (lane & 15)];
  __syncthreads();
  // P1: node update MFMAs from T0 (emb) + T1 (aggr)
  f32x4 accU[4] = {};
  f32x4 accR[4] = {};
  #pragma unroll
  for (int ks = 0; ks < 4; ++ks) {
    int k0 = ks * 32;
    bf16x8 bU1 = *(const bf16x8*)(U1t + (size_t)(c0 + arow) * 128 + k0 + kb);
    bf16x8 bU2 = *(const bf16x8*)(U2t + (size_t)(c0 + arow) * 128 + k0 + kb);
    bf16x8 bR  = *(const bf16x8*)(Rt  + (size_t)(c0 + arow) * 128 + k0 + kb);
    #pragma unroll
    for (int rt = 0; rt < 4; ++rt) {
      int r = rt * 16 + arow;
      int byte = (r * 256 + (k0 + kb) * 2) ^ ((r & 7) << 4);
      bf16x8 aE = *(const bf16x8*)((const char*)T0 + byte);
      bf16x8 aA = *(const bf16x8*)((const char*)T1 + byte);
      accU[rt] = __builtin_amdgcn_mfma_f32_16x16x32_bf16(aE, bU1, accU[rt], 0, 0, 0);
      accU[rt] = __builtin_amdgcn_mfma_f32_16x16x32_bf16(aA, bU2, accU[rt], 0, 0, 0);
      accR[rt] = __builtin_amdgcn_mfma_f32_16x16x32_bf16(aE, bR,  accR[rt], 0, 0, 0);
    }
  }
  __syncthreads();   // all T0/T1 reads done
  // epilogue: X -> T0 (in place over dead emb tile)
  {
    int ccol = lane & 15, crow4 = (lane >> 4) * 4;
    int cc = c0 + ccol;
    #pragma unroll
    for (int rt = 0; rt < 4; ++rt)
      #pragma unroll
      for (int j = 0; j < 4; ++j) {
        int lrow = rt * 16 + crow4 + j;
        int lbyte = (lrow * 256 + cc * 2) ^ ((lrow & 7) << 4);
        *(unsigned short*)((char*)T0 + lbyte) =
            f2bf(accR[rt][j] + fmaxf(accU[rt][j] + uB, 0.f));
      }
  }
  __syncthreads();   // X complete
  // P2: dual GEMM from T0 (X); vstore out; stage acc1 -> T1 (dead)
  f32x4 acc1[4] = {};
  f32x4 acc2[4] = {};
  #pragma unroll
  for (int ks = 0; ks < 4; ++ks) {
    int k0 = ks * 32;
    bf16x8 b1 = *(const bf16x8*)(W1t + (size_t)(c0 + arow) * 128 + k0 + kb);
    bf16x8 b2 = *(const bf16x8*)(W2t + (size_t)(c0 + arow) * 128 + k0 + kb);
    #pragma unroll
    for (int rt = 0; rt < 4; ++rt) {
      int r = rt * 16 + arow;
      int byte = (r * 256 + (k0 + kb) * 2) ^ ((r & 7) << 4);
      bf16x8 a = *(const bf16x8*)((const char*)T0 + byte);
      acc1[rt] = __builtin_amdgcn_mfma_f32_16x16x32_bf16(a, b1, acc1[rt], 0, 0, 0);
      acc2[rt] = __builtin_amdgcn_mfma_f32_16x16x32_bf16(a, b2, acc2[rt], 0, 0, 0);
    }
  }
  vstore_tile64<512>(out, T0, row0, n, tid);
  epi_to_lds64(T1, acc1, lane, c0);
  __syncthreads();
  vstore_tile64<512>(Y1, T1, row0, n, tid);
  __syncthreads();
  epi_to_lds64(T1, acc2, lane, c0);
  __syncthreads();
  vstore_tile64<512>(Y2, T1, row0, n, tid);
}

// ---------------- fused pull + final node update + pooling partials (shfl reduce) ----------------
__global__ __launch_bounds__(512, 4) void k_node_pool_pull(
    const unsigned short* __restrict__ emb,
    const int* __restrict__ starts, const int2* __restrict__ spack,
    const unsigned short* __restrict__ Agth, const unsigned short* __restrict__ Bm,
    const float* __restrict__ wd, const float* __restrict__ mb,
    const unsigned short* __restrict__ U1t, const unsigned short* __restrict__ U2t,
    const unsigned short* __restrict__ Rt, const float* __restrict__ updb,
    const int* __restrict__ batch,
    float* __restrict__ ppart, int* __restrict__ pgid, int n) {
  __shared__ unsigned short Es[64 * 128];
  __shared__ unsigned short As[64 * 128];
  __shared__ int sbat[64];
  int row0 = blockIdx.x * 64;
  int tid = threadIdx.x;
  int wave = tid >> 6, lane = tid & 63;
  int c0 = wave * 16;
  int arow = lane & 15, kb = (lane >> 4) * 8;
  stage_tile64<512>(Es, emb, row0, n, tid);
  if (tid < 64) sbat[tid] = batch[min(row0 + tid, n - 1)];
  gather_aggr_lds(As, starts, spack, Agth, Bm, wd, mb, row0, n, tid);
  float uB = updb[c0 + (lane & 15)];
  __syncthreads();
  f32x4 accU[4] = {};
  f32x4 accR[4] = {};
  #pragma unroll
  for (int ks = 0; ks < 4; ++ks) {
    int k0 = ks * 32;
    bf16x8 bU1 = *(const bf16x8*)(U1t + (size_t)(c0 + arow) * 128 + k0 + kb);
    bf16x8 bU2 = *(const bf16x8*)(U2t + (size_t)(c0 + arow) * 128 + k0 + kb);
    bf16x8 bR  = *(const bf16x8*)(Rt  + (size_t)(c0 + arow) * 128 + k0 + kb);
    #pragma unroll
    for (int rt = 0; rt < 4; ++rt) {
      int r = rt * 16 + arow;
      int byte = (r * 256 + (k0 + kb) * 2) ^ ((r & 7) << 4);
      bf16x8 aE = *(const bf16x8*)((const char*)Es + byte);
      bf16x8 aA = *(const bf16x8*)((const char*)As + byte);
      accU[rt] = __builtin_amdgcn_mfma_f32_16x16x32_bf16(aE, bU1, accU[rt], 0, 0, 0);
      accU[rt] = __builtin_amdgcn_mfma_f32_16x16x32_bf16(aA, bU2, accU[rt], 0, 0, 0);
      accR[rt] = __builtin_amdgcn_mfma_f32_16x16x32_bf16(aE, bR,  accR[rt], 0, 0, 0);
    }
  }
  // per-thread bucket sums over its 16 rows, then shfl-fold lane-groups
  int g0 = sbat[0];
  int crow4 = (lane >> 4) * 4;
  float s0 = 0.f, s1 = 0.f;
  #pragma unroll
  for (int rt = 0; rt < 4; ++rt)
    #pragma unroll
    for (int j = 0; j < 4; ++j) {
      int lrow = rt * 16 + crow4 + j;
      if (row0 + lrow < n) {
        float v = accR[rt][j] + fmaxf(accU[rt][j] + uB, 0.f);
        if (sbat[lrow] == g0) s0 += v; else s1 += v;
      }
    }
  s0 += __shfl_xor(s0, 16); s0 += __shfl_xor(s0, 32);
  s1 += __shfl_xor(s1, 16); s1 += __shfl_xor(s1, 32);
  if ((lane >> 4) == 0) {
    int cc = c0 + (lane & 15);
    ppart[(size_t)(2 * blockIdx.x) * 128 + cc] = s0;
    ppart[(size_t)(2 * blockIdx.x + 1) * 128 + cc] = s1;
  }
  if (tid == 0) {
    int gl = sbat[63];
    pgid[2 * blockIdx.x] = g0;
    pgid[2 * blockIdx.x + 1] = (gl != g0) ? gl : -1;
  }
}

// ---------------- pool reduce: per-graph sum of block partials / count ----------------
__global__ __launch_bounds__(128) void k_pool2(const float* __restrict__ ppart,
                                               const int* __restrict__ pgid,
                                               const int* __restrict__ gstart,
                                               float* __restrict__ pooled) {
  int g = blockIdx.x, t = threadIdx.x;
  int blo = gstart[g] >> 6;
  int bhi = (gstart[g + 1] - 1) >> 6;
  float acc = 0.f;
  for (int b = blo; b <= bhi; ++b) {
    if (pgid[2 * b] == g)     acc += ppart[(size_t)(2 * b) * 128 + t];
    if (pgid[2 * b + 1] == g) acc += ppart[(size_t)(2 * b + 1) * 128 + t];
  }
  float cntf = (float)(gstart[g + 1] - gstart[g]);
  pooled[g * 128 + t] = acc / fmaxf(cntf, 1.f);
}

// ---------------- task head: 4-layer MLP per (graph, task) row (fp32) ----------------
__global__ __launch_bounds__(128) void k_head(
    const float* __restrict__ pooled, const float* __restrict__ temb,
    const int* __restrict__ tasks,
    const float* __restrict__ W0, const float* __restrict__ b0,
    const float* __restrict__ W1, const float* __restrict__ b1,
    const float* __restrict__ W2, const float* __restrict__ b2,
    const float* __restrict__ W3, const float* __restrict__ b3,
    float* __restrict__ out) {
  __shared__ float f[192];
  __shared__ float za[128];
  __shared__ float zb[128];
  int rowi = blockIdx.x, t = threadIdx.x;
  int proto = tasks[rowi*2 + 0];
  int tid2  = tasks[rowi*2 + 1];
  f[t] = pooled[proto*128 + t];
  if (t < 64) f[128 + t] = temb[(size_t)tid2*64 + t];
  __syncthreads();
  float a = b0[t];
  for (int k = 0; k < 192; ++k) a += f[k] * W0[k*128 + t];
  za[t] = fmaxf(a, 0.f);
  __syncthreads();
  a = b1[t];
  for (int k = 0; k < 128; ++k) a += za[k] * W1[k*128 + t];
  zb[t] = fmaxf(a, 0.f);
  __syncthreads();
  a = b2[t];
  for (int k = 0; k < 128; ++k) a += zb[k] * W2[k*128 + t];
  za[t] = fmaxf(a, 0.f);
  __syncthreads();
  if (t < 3) {
    a = b3[t];
    for (int k = 0; k < 128; ++k) a += za[k] * W3[k*3 + t];
    out[rowi*3 + t] = a;
  }
}

extern "C" void kernel_launch(void* const* d_in, const int* in_sizes, int n_in,
                              void* d_out, int out_size, void* d_ws, size_t ws_size,
                              hipStream_t stream) {
  const float* h    = (const float*)d_in[0];
  const float* x    = (const float*)d_in[1];
  const int*   ei   = (const int*)d_in[2];
  const int*   batch= (const int*)d_in[4];
  const int*   tasks= (const int*)d_in[5];
  const float* embW = (const float*)d_in[7];
  const float* embB = (const float*)d_in[8];
  const float* resW = (const float*)d_in[9];
  const float* msgW = (const float*)d_in[10];
  const float* msgB = (const float*)d_in[11];
  const float* updW = (const float*)d_in[12];
  const float* updB = (const float*)d_in[13];
  const float* W0 = (const float*)d_in[14]; const float* b0 = (const float*)d_in[15];
  const float* W1 = (const float*)d_in[16]; const float* b1 = (const float*)d_in[17];
  const float* W2 = (const float*)d_in[18]; const float* b2 = (const float*)d_in[19];
  const float* W3 = (const float*)d_in[20]; const float* b3 = (const float*)d_in[21];
  const float* temb = (const float*)d_in[22];
  const int* row = ei;
  const int* col = ei + NE;

  // bf16 buffers first (16B alignment), then fp32, then int2/int
  unsigned short* bws = (unsigned short*)d_ws;
  unsigned short* e0   = bws;  bws += (size_t)NN*128;
  unsigned short* e1   = bws;  bws += (size_t)NN*128;
  unsigned short* A0   = bws;  bws += (size_t)NN*128;
  unsigned short* B0   = bws;  bws += (size_t)NN*128;
  unsigned short* A1   = bws;  bws += (size_t)NN*128;
  unsigned short* B1   = bws;  bws += (size_t)NN*128;
  unsigned short* wbf  = bws;  bws += 10*16384 + 8192;
  float* ws = (float*)bws;
  float* pooled= ws;  ws += NB*128;
  float* ppart = ws;  ws += (size_t)2*NBLK64*128;
  int2*  spack = (int2*)ws;
  int*   iws   = (int*)(spack + NE);
  int*   cnt    = iws;  iws += NN;
  int*   starts = iws;  iws += NN + 1;
  int*   cursor = iws;  iws += NN;
  int*   gstart = iws;  iws += NB + 1;
  int*   bsum   = iws;  iws += 256;
  int*   pgid   = iws;  iws += 2*NBLK64;

  const unsigned short* embWt = wbf + (size_t)10*16384;

  // weight prep + cnt zero
  k_wprep<<<672, 256, 0, stream>>>(msgW, updW, resW, embW, wbf, cnt);

  // CSR build (by destination col) + graph starts
  k_count_gstart<<<(NE + 255)/256, 256, 0, stream>>>(col, cnt, batch, gstart);
  k_scan1<<<SCB, 256, 0, stream>>>(cnt, starts, bsum);
  k_scan2<<<1, 256, 0, stream>>>(bsum);
  k_scan3<<<SCB, 256, 0, stream>>>(starts, bsum, cursor);
  k_scatter<<<(NE + 255)/256, 256, 0, stream>>>(row, col, x, cursor, spack);

  const unsigned short* m0W1t = wbf + (size_t)0 * 16384;
  const unsigned short* m0W2t = wbf + (size_t)1 * 16384;
  const unsigned short* u0W1t = wbf + (size_t)2 * 16384;
  const unsigned short* u0W2t = wbf + (size_t)3 * 16384;
  const unsigned short* r0Wt  = wbf + (size_t)4 * 16384;
  const unsigned short* m1W1t = wbf + (size_t)5 * 16384;
  const unsigned short* m1W2t = wbf + (size_t)6 * 16384;
  const unsigned short* u1W1t = wbf + (size_t)7 * 16384;
  const unsigned short* u1W2t = wbf + (size_t)8 * 16384;
  const unsigned short* r1Wt  = wbf + (size_t)9 * 16384;

  // embed + layer-0 dual msg GEMM
  k_embed_dual<<<NBLK64, 512, 0, stream>>>(h, embWt, embB, m0W1t, m0W2t,
                                           e0, A0, B0, NN);
  // layer 0: fused pull + node update + layer-1 dual GEMM  (A0/B0 -> e1, A1, B1)
  k_node_dual_pull<<<NBLK64, 512, 0, stream>>>(e0, starts, spack, A0, B0,
                                               msgW + 256*128, msgB,
                                               u0W1t, u0W2t, r0Wt, updB,
                                               m1W1t, m1W2t, e1, A1, B1, NN);
  // layer 1: fused pull + node update + pooling partials  (A1/B1 + e1 -> ppart)
  k_node_pool_pull<<<NBLK64, 512, 0, stream>>>(e1, starts, spack, A1, B1,
                                               msgW + (size_t)257*128 + 256*128,
                                               msgB + 128,
                                               u1W1t, u1W2t, r1Wt, updB + 128,
                                               batch, ppart, pgid, NN);
  k_pool2<<<NB, 128, 0, stream>>>(ppart, pgid, gstart, pooled);
  k_head<<<NTROWS, 128, 0, stream>>>(pooled, temb, tasks,
                                     W0, b0, W1, b1, W2, b2, W3, b3, (float*)d_out);
}

// Round 16
// 196.490 us; speedup vs baseline: 1.1045x; 1.0629x over previous
//
#include <hip/hip_runtime.h>

constexpr int NN = 50000;   // nodes
constexpr int NE = 500000;  // edges
constexpr int NB = 32;      // graphs
constexpr int NTROWS = 256; // B * TASKS_PER
constexpr int SCB = 196;    // ceil(NN/256) scan blocks
constexpr int NBLK64 = (NN + 63) / 64;  // 782 row-tiles of 64
constexpr int SCAT_BLK = (NE + 511) / 512;  // 977 scatter blocks @512

typedef __attribute__((ext_vector_type(8))) short bf16x8;
typedef __attribute__((ext_vector_type(4))) float f32x4;

static __device__ __forceinline__ unsigned short f2bf(float f) {
  unsigned u = __float_as_uint(f);
  unsigned r = (u + 0x7FFFu + ((u >> 16) & 1u)) >> 16;  // RNE
  return (unsigned short)r;
}
static __device__ __forceinline__ float bf2f(unsigned short s) {
  return __uint_as_float(((unsigned)s) << 16);
}

// ---------------- fused: weight prep (blocks 0..671) + CSR histogram/gstart (rest) ----------------
__global__ void k_prep_count(const float* __restrict__ msgW, const float* __restrict__ updW,
                             const float* __restrict__ resW, const float* __restrict__ embW,
                             unsigned short* __restrict__ wbf,
                             const int* __restrict__ col, int* __restrict__ cnt,
                             const int* __restrict__ batch, int* __restrict__ gstart) {
  if (blockIdx.x < 672) {
    int idx = blockIdx.x * 256 + threadIdx.x;  // 10*16384 + 8192 = 172032 = 672*256
    if (idx >= 10 * 16384 + 8192) return;
    if (idx < 10 * 16384) {
      int m = idx >> 14, e = idx & 16383;
      int nn = e >> 7, kk = e & 127;
      int l = m / 5, t = m % 5;
      const float* src;
      if (t == 0)      src = msgW + (size_t)l * 257 * 128;
      else if (t == 1) src = msgW + (size_t)l * 257 * 128 + 128 * 128;
      else if (t == 2) src = updW + (size_t)l * 256 * 128;
      else if (t == 3) src = updW + (size_t)l * 256 * 128 + 128 * 128;
      else             src = resW + (size_t)l * 128 * 128;
      wbf[idx] = f2bf(src[kk * 128 + nn]);
    } else {
      int e = idx - 10 * 16384;          // embW^T: [128 n][64 k]
      int nn = e >> 6, kk = e & 63;
      wbf[idx] = f2bf(embW[kk * 128 + nn]);
    }
  } else {
    int e = (blockIdx.x - 672) * 256 + threadIdx.x;
    if (e < NE) atomicAdd(&cnt[col[e]], 1);
    if (e < NN) {
      int b = batch[e];
      if (e == 0) gstart[b] = 0;
      else if (batch[e - 1] != b) gstart[b] = e;
      if (e == NN - 1) gstart[b + 1] = NN;
    }
  }
}

// ---------------- scan stage 1: per-block exclusive scan + block sums ----------------
__global__ __launch_bounds__(256) void k_scan1(const int* __restrict__ cnt,
                                               int* __restrict__ starts,
                                               int* __restrict__ bsum) {
  __shared__ int s[256];
  int t = threadIdx.x;
  int i = blockIdx.x * 256 + t;
  int v = (i < NN) ? cnt[i] : 0;
  s[t] = v; __syncthreads();
  for (int off = 1; off < 256; off <<= 1) {
    int u = (t >= off) ? s[t - off] : 0;
    __syncthreads();
    s[t] += u;
    __syncthreads();
  }
  if (i < NN) starts[i] = s[t] - v;
  if (t == 255) bsum[blockIdx.x] = s[255];
}

// ---------------- scan stage 2+3 fused: block offset via in-block reduction ----------------
__global__ __launch_bounds__(256) void k_scan3b(int* __restrict__ starts,
                                                const int* __restrict__ bsum,
                                                int* __restrict__ cursor) {
  __shared__ int red[256];
  int t = threadIdx.x;
  red[t] = (t < (int)blockIdx.x && t < SCB) ? bsum[t] : 0;
  __syncthreads();
  #pragma unroll
  for (int s = 128; s > 0; s >>= 1) {
    if (t < s) red[t] += red[t + s];
    __syncthreads();
  }
  int off = red[0];
  int i = blockIdx.x * 256 + t;
  if (i < NN) {
    int v = starts[i] + off;
    starts[i] = v;
    cursor[i] = v;
  }
  if (i == 0) starts[NN] = NE;
}

// ---------------- staging: bf16 64-row tile -> swizzled LDS (pure copy) ----------------
template<int TPB>
static __device__ __forceinline__ void stage_tile64(
    unsigned short* lds, const unsigned short* __restrict__ src, int row0, int n, int tid) {
  #pragma unroll
  for (int ch = tid; ch < 1024; ch += TPB) {    // 64 rows * 16 chunks of 16B
    int r = ch >> 4, kc = ch & 15;
    bf16x8 v = {0,0,0,0,0,0,0,0};
    if (row0 + r < n) v = *(const bf16x8*)(src + (size_t)(row0 + r) * 128 + kc * 8);
    int byte = (r * 256 + kc * 16) ^ ((r & 7) << 4);
    *(bf16x8*)((char*)lds + byte) = v;
  }
}

// ---------------- vector store: swizzled 64-row LDS tile -> global row-major bf16 ----------------
template<int TPB>
static __device__ __forceinline__ void vstore_tile64(
    unsigned short* __restrict__ dst, const unsigned short* lds, int row0, int n, int tid) {
  #pragma unroll
  for (int ch = tid; ch < 1024; ch += TPB) {
    int r = ch >> 4, kc = ch & 15;
    if (row0 + r < n) {
      bf16x8 v = *(const bf16x8*)((const char*)lds + ((r * 256 + kc * 16) ^ ((r & 7) << 4)));
      *(bf16x8*)(dst + (size_t)(row0 + r) * 128 + kc * 8) = v;
    }
  }
}

// ---------------- epilogue: C-frags (f32, 4 row-tiles x 1 col-tile) -> swizzled LDS ----------------
static __device__ __forceinline__ void epi_to_lds64(
    unsigned short* lds, const f32x4 (&acc)[4], int lane, int c0) {
  int ccol = lane & 15, crow4 = (lane >> 4) * 4;
  int cc = c0 + ccol;
  #pragma unroll
  for (int rt = 0; rt < 4; ++rt)
    #pragma unroll
    for (int j = 0; j < 4; ++j) {
      int lrow = rt * 16 + crow4 + j;
      int lbyte = (lrow * 256 + cc * 2) ^ ((lrow & 7) << 4);
      *(unsigned short*)((char*)lds + lbyte) = f2bf(acc[rt][j]);
    }
}

// ---------------- in-kernel pull (R13 variant): 16 lanes/node, 2 sequential passes ----------------
static __device__ __forceinline__ void gather_aggr_lds(
    unsigned short* As, const int* __restrict__ starts, const int2* __restrict__ spack,
    const unsigned short* __restrict__ A, const unsigned short* __restrict__ Bm,
    const float* __restrict__ wd, const float* __restrict__ mb,
    int row0, int n, int tid) {
  int c0 = (tid & 15) * 8;
  float4 w0 = *(const float4*)(wd + c0), w1 = *(const float4*)(wd + c0 + 4);
  float4 bb0 = *(const float4*)(mb + c0), bb1 = *(const float4*)(mb + c0 + 4);
  float wv[8] = {w0.x, w0.y, w0.z, w0.w, w1.x, w1.y, w1.z, w1.w};
  float bv[8] = {bb0.x, bb0.y, bb0.z, bb0.w, bb1.x, bb1.y, bb1.z, bb1.w};
  #pragma unroll
  for (int pass = 0; pass < 2; ++pass) {
    int lr = (tid >> 4) + pass * 32;      // local row 0..63
    int node = row0 + lr;
    union { bf16x8 v; unsigned short s[8]; } o;
    if (node < n) {
      union { bf16x8 v; unsigned short s[8]; } ub;
      ub.v = *(const bf16x8*)(Bm + (size_t)node * 128 + c0);
      float basev[8], accv[8];
      #pragma unroll
      for (int j = 0; j < 8; ++j) { basev[j] = bf2f(ub.s[j]) + bv[j]; accv[j] = 0.f; }
      int s = starts[node], e = starts[node + 1];
      int i = s;
      for (; i + 4 <= e; i += 4) {
        int2 p0 = spack[i + 0], p1 = spack[i + 1];
        int2 p2 = spack[i + 2], p3 = spack[i + 3];
        union { bf16x8 v; unsigned short s[8]; } a0, a1, a2, a3;
        a0.v = *(const bf16x8*)(A + (size_t)p0.x * 128 + c0);
        a1.v = *(const bf16x8*)(A + (size_t)p1.x * 128 + c0);
        a2.v = *(const bf16x8*)(A + (size_t)p2.x * 128 + c0);
        a3.v = *(const bf16x8*)(A + (size_t)p3.x * 128 + c0);
        float d0 = __int_as_float(p0.y), d1 = __int_as_float(p1.y);
        float d2 = __int_as_float(p2.y), d3 = __int_as_float(p3.y);
        #pragma unroll
        for (int j = 0; j < 8; ++j) {
          accv[j] += fmaxf(bf2f(a0.s[j]) + fmaf(d0, wv[j], basev[j]), 0.f);
          accv[j] += fmaxf(bf2f(a1.s[j]) + fmaf(d1, wv[j], basev[j]), 0.f);
          accv[j] += fmaxf(bf2f(a2.s[j]) + fmaf(d2, wv[j], basev[j]), 0.f);
          accv[j] += fmaxf(bf2f(a3.s[j]) + fmaf(d3, wv[j], basev[j]), 0.f);
        }
      }
      for (; i < e; ++i) {
        int2 p = spack[i];
        union { bf16x8 v; unsigned short s[8]; } a;
        a.v = *(const bf16x8*)(A + (size_t)p.x * 128 + c0);
        float d = __int_as_float(p.y);
        #pragma unroll
        for (int j = 0; j < 8; ++j)
          accv[j] += fmaxf(bf2f(a.s[j]) + fmaf(d, wv[j], basev[j]), 0.f);
      }
      #pragma unroll
      for (int j = 0; j < 8; ++j) o.s[j] = f2bf(accv[j]);
    } else {
      #pragma unroll
      for (int j = 0; j < 8; ++j) o.s[j] = 0;
    }
    int byte = (lr * 256 + (tid & 15) * 16) ^ ((lr & 7) << 4);
    *(bf16x8*)((char*)As + byte) = o.v;
  }
}

// ---------------- fused: embed+dual GEMM (blocks 0..NBLK64-1) ∪ edge scatter (rest) ----------------
__global__ __launch_bounds__(512) void k_scatter_embed(
    const float* __restrict__ h, const unsigned short* __restrict__ embWt,
    const float* __restrict__ embB,
    const unsigned short* __restrict__ W1t, const unsigned short* __restrict__ W2t,
    unsigned short* __restrict__ emb, unsigned short* __restrict__ Y1,
    unsigned short* __restrict__ Y2, int n,
    const int* __restrict__ row, const int* __restrict__ col,
    const float* __restrict__ x, int* __restrict__ cursor, int2* __restrict__ spack) {
  __shared__ unsigned short T0[64 * 128];
  __shared__ unsigned short T1[64 * 128];
  int tid = threadIdx.x;
  if (blockIdx.x >= NBLK64) {
    // -------- scatter branch --------
    int e = (blockIdx.x - NBLK64) * 512 + tid;
    if (e < NE) {
      int r = row[e], c = col[e];
      float dx = x[3*r+0] - x[3*c+0];
      float dy = x[3*r+1] - x[3*c+1];
      float dz = x[3*r+2] - x[3*c+2];
      float d = dx*dx + dy*dy + dz*dz;
      int pos = atomicAdd(&cursor[c], 1);
      spack[pos] = make_int2(r, __float_as_int(d));
    }
    return;
  }
  // -------- embed + dual GEMM branch --------
  int row0 = blockIdx.x * 64;
  int wave = tid >> 6, lane = tid & 63;
  int c0 = wave * 16;
  int arow = lane & 15, kb = (lane >> 4) * 8;
  {  // stage h tile fp32 -> bf16 into T0 (Hs layout: row stride 128 B)
    int r = tid >> 3, kc = tid & 7;
    union { bf16x8 v; unsigned short s[8]; } u;
    if (row0 + r < n) {
      const float* p = h + (size_t)(row0 + r) * 64 + kc * 8;
      float4 f0 = *(const float4*)p, f1 = *(const float4*)(p + 4);
      u.s[0]=f2bf(f0.x); u.s[1]=f2bf(f0.y); u.s[2]=f2bf(f0.z); u.s[3]=f2bf(f0.w);
      u.s[4]=f2bf(f1.x); u.s[5]=f2bf(f1.y); u.s[6]=f2bf(f1.z); u.s[7]=f2bf(f1.w);
    } else {
      #pragma unroll
      for (int j = 0; j < 8; ++j) u.s[j] = 0;
    }
    int byte = (r * 128 + kc * 16) ^ ((r & 7) << 4);
    *(bf16x8*)((char*)T0 + byte) = u.v;
  }
  float bB = embB[c0 + (lane & 15)];
  __syncthreads();
  f32x4 accE[4] = {};
  #pragma unroll
  for (int ks = 0; ks < 2; ++ks) {
    bf16x8 b = *(const bf16x8*)(embWt + (size_t)(c0 + arow) * 64 + ks * 32 + kb);
    #pragma unroll
    for (int rt = 0; rt < 4; ++rt) {
      int r = rt * 16 + arow;
      int byte = (r * 128 + (ks * 32 + kb) * 2) ^ ((r & 7) << 4);
      bf16x8 a = *(const bf16x8*)((const char*)T0 + byte);
      accE[rt] = __builtin_amdgcn_mfma_f32_16x16x32_bf16(a, b, accE[rt], 0, 0, 0);
    }
  }
  {
    int ccol = lane & 15, crow4 = (lane >> 4) * 4;
    int cc = c0 + ccol;
    #pragma unroll
    for (int rt = 0; rt < 4; ++rt)
      #pragma unroll
      for (int j = 0; j < 4; ++j) {
        int lrow = rt * 16 + crow4 + j;
        int lbyte = (lrow * 256 + cc * 2) ^ ((lrow & 7) << 4);
        *(unsigned short*)((char*)T1 + lbyte) = f2bf(accE[rt][j] + bB);
      }
  }
  __syncthreads();
  f32x4 acc1[4] = {};
  f32x4 acc2[4] = {};
  #pragma unroll
  for (int ks = 0; ks < 4; ++ks) {
    int k0 = ks * 32;
    bf16x8 b1 = *(const bf16x8*)(W1t + (size_t)(c0 + arow) * 128 + k0 + kb);
    bf16x8 b2 = *(const bf16x8*)(W2t + (size_t)(c0 + arow) * 128 + k0 + kb);
    #pragma unroll
    for (int rt = 0; rt < 4; ++rt) {
      int r = rt * 16 + arow;
      int byte = (r * 256 + (k0 + kb) * 2) ^ ((r & 7) << 4);
      bf16x8 a = *(const bf16x8*)((const char*)T1 + byte);
      acc1[rt] = __builtin_amdgcn_mfma_f32_16x16x32_bf16(a, b1, acc1[rt], 0, 0, 0);
      acc2[rt] = __builtin_amdgcn_mfma_f32_16x16x32_bf16(a, b2, acc2[rt], 0, 0, 0);
    }
  }
  vstore_tile64<512>(emb, T1, row0, n, tid);
  epi_to_lds64(T0, acc1, lane, c0);
  __syncthreads();
  vstore_tile64<512>(Y1, T0, row0, n, tid);
  __syncthreads();
  epi_to_lds64(T0, acc2, lane, c0);
  __syncthreads();
  vstore_tile64<512>(Y2, T0, row0, n, tid);
}

// ---------------- fused pull + node update + next-layer dual GEMM, 2-tile LDS ----------------
__global__ __launch_bounds__(512, 4) void k_node_dual_pull(
    const unsigned short* __restrict__ emb,
    const int* __restrict__ starts, const int2* __restrict__ spack,
    const unsigned short* __restrict__ Agth, const unsigned short* __restrict__ Bm,
    const float* __restrict__ wd, const float* __restrict__ mb,
    const unsigned short* __restrict__ U1t, const unsigned short* __restrict__ U2t,
    const unsigned short* __restrict__ Rt, const float* __restrict__ updb,
    const unsigned short* __restrict__ W1t, const unsigned short* __restrict__ W2t,
    unsigned short* __restrict__ out, unsigned short* __restrict__ Y1,
    unsigned short* __restrict__ Y2, int n) {
  __shared__ unsigned short T0[64 * 128];   // emb, then X
  __shared__ unsigned short T1[64 * 128];   // aggr, then Y1, then Y2
  int row0 = blockIdx.x * 64;
  int tid = threadIdx.x;
  int wave = tid >> 6, lane = tid & 63;
  int c0 = wave * 16;
  int arow = lane & 15, kb = (lane >> 4) * 8;
  stage_tile64<512>(T0, emb, row0, n, tid);
  gather_aggr_lds(T1, starts, spack, Agth, Bm, wd, mb, row0, n, tid);
  float uB = updb[c0 + (lane & 15)];
  __syncthreads();
  f32x4 accU[4] = {};
  f32x4 accR[4] = {};
  #pragma unroll
  for (int ks = 0; ks < 4; ++ks) {
    int k0 = ks * 32;
    bf16x8 bU1 = *(const bf16x8*)(U1t + (size_t)(c0 + arow) * 128 + k0 + kb);
    bf16x8 bU2 = *(const bf16x8*)(U2t + (size_t)(c0 + arow) * 128 + k0 + kb);
    bf16x8 bR  = *(const bf16x8*)(Rt  + (size_t)(c0 + arow) * 128 + k0 + kb);
    #pragma unroll
    for (int rt = 0; rt < 4; ++rt) {
      int r = rt * 16 + arow;
      int byte = (r * 256 + (k0 + kb) * 2) ^ ((r & 7) << 4);
      bf16x8 aE = *(const bf16x8*)((const char*)T0 + byte);
      bf16x8 aA = *(const bf16x8*)((const char*)T1 + byte);
      accU[rt] = __builtin_amdgcn_mfma_f32_16x16x32_bf16(aE, bU1, accU[rt], 0, 0, 0);
      accU[rt] = __builtin_amdgcn_mfma_f32_16x16x32_bf16(aA, bU2, accU[rt], 0, 0, 0);
      accR[rt] = __builtin_amdgcn_mfma_f32_16x16x32_bf16(aE, bR,  accR[rt], 0, 0, 0);
    }
  }
  __syncthreads();   // all T0/T1 reads done
  {
    int ccol = lane & 15, crow4 = (lane >> 4) * 4;
    int cc = c0 + ccol;
    #pragma unroll
    for (int rt = 0; rt < 4; ++rt)
      #pragma unroll
      for (int j = 0; j < 4; ++j) {
        int lrow = rt * 16 + crow4 + j;
        int lbyte = (lrow * 256 + cc * 2) ^ ((lrow & 7) << 4);
        *(unsigned short*)((char*)T0 + lbyte) =
            f2bf(accR[rt][j] + fmaxf(accU[rt][j] + uB, 0.f));
      }
  }
  __syncthreads();   // X complete
  f32x4 acc1[4] = {};
  f32x4 acc2[4] = {};
  #pragma unroll
  for (int ks = 0; ks < 4; ++ks) {
    int k0 = ks * 32;
    bf16x8 b1 = *(const bf16x8*)(W1t + (size_t)(c0 + arow) * 128 + k0 + kb);
    bf16x8 b2 = *(const bf16x8*)(W2t + (size_t)(c0 + arow) * 128 + k0 + kb);
    #pragma unroll
    for (int rt = 0; rt < 4; ++rt) {
      int r = rt * 16 + arow;
      int byte = (r * 256 + (k0 + kb) * 2) ^ ((r & 7) << 4);
      bf16x8 a = *(const bf16x8*)((const char*)T0 + byte);
      acc1[rt] = __builtin_amdgcn_mfma_f32_16x16x32_bf16(a, b1, acc1[rt], 0, 0, 0);
      acc2[rt] = __builtin_amdgcn_mfma_f32_16x16x32_bf16(a, b2, acc2[rt], 0, 0, 0);
    }
  }
  vstore_tile64<512>(out, T0, row0, n, tid);
  epi_to_lds64(T1, acc1, lane, c0);
  __syncthreads();
  vstore_tile64<512>(Y1, T1, row0, n, tid);
  __syncthreads();
  epi_to_lds64(T1, acc2, lane, c0);
  __syncthreads();
  vstore_tile64<512>(Y2, T1, row0, n, tid);
}

// ---------------- fused pull + final node update + pooling partials (shfl reduce) ----------------
__global__ __launch_bounds__(512, 4) void k_node_pool_pull(
    const unsigned short* __restrict__ emb,
    const int* __restrict__ starts, const int2* __restrict__ spack,
    const unsigned short* __restrict__ Agth, const unsigned short* __restrict__ Bm,
    const float* __restrict__ wd, const float* __restrict__ mb,
    const unsigned short* __restrict__ U1t, const unsigned short* __restrict__ U2t,
    const unsigned short* __restrict__ Rt, const float* __restrict__ updb,
    const int* __restrict__ batch,
    float* __restrict__ ppart, int* __restrict__ pgid, int n) {
  __shared__ unsigned short Es[64 * 128];
  __shared__ unsigned short As[64 * 128];
  __shared__ int sbat[64];
  int row0 = blockIdx.x * 64;
  int tid = threadIdx.x;
  int wave = tid >> 6, lane = tid & 63;
  int c0 = wave * 16;
  int arow = lane & 15, kb = (lane >> 4) * 8;
  stage_tile64<512>(Es, emb, row0, n, tid);
  if (tid < 64) sbat[tid] = batch[min(row0 + tid, n - 1)];
  gather_aggr_lds(As, starts, spack, Agth, Bm, wd, mb, row0, n, tid);
  float uB = updb[c0 + (lane & 15)];
  __syncthreads();
  f32x4 accU[4] = {};
  f32x4 accR[4] = {};
  #pragma unroll
  for (int ks = 0; ks < 4; ++ks) {
    int k0 = ks * 32;
    bf16x8 bU1 = *(const bf16x8*)(U1t + (size_t)(c0 + arow) * 128 + k0 + kb);
    bf16x8 bU2 = *(const bf16x8*)(U2t + (size_t)(c0 + arow) * 128 + k0 + kb);
    bf16x8 bR  = *(const bf16x8*)(Rt  + (size_t)(c0 + arow) * 128 + k0 + kb);
    #pragma unroll
    for (int rt = 0; rt < 4; ++rt) {
      int r = rt * 16 + arow;
      int byte = (r * 256 + (k0 + kb) * 2) ^ ((r & 7) << 4);
      bf16x8 aE = *(const bf16x8*)((const char*)Es + byte);
      bf16x8 aA = *(const bf16x8*)((const char*)As + byte);
      accU[rt] = __builtin_amdgcn_mfma_f32_16x16x32_bf16(aE, bU1, accU[rt], 0, 0, 0);
      accU[rt] = __builtin_amdgcn_mfma_f32_16x16x32_bf16(aA, bU2, accU[rt], 0, 0, 0);
      accR[rt] = __builtin_amdgcn_mfma_f32_16x16x32_bf16(aE, bR,  accR[rt], 0, 0, 0);
    }
  }
  int g0 = sbat[0];
  int crow4 = (lane >> 4) * 4;
  float s0 = 0.f, s1 = 0.f;
  #pragma unroll
  for (int rt = 0; rt < 4; ++rt)
    #pragma unroll
    for (int j = 0; j < 4; ++j) {
      int lrow = rt * 16 + crow4 + j;
      if (row0 + lrow < n) {
        float v = accR[rt][j] + fmaxf(accU[rt][j] + uB, 0.f);
        if (sbat[lrow] == g0) s0 += v; else s1 += v;
      }
    }
  s0 += __shfl_xor(s0, 16); s0 += __shfl_xor(s0, 32);
  s1 += __shfl_xor(s1, 16); s1 += __shfl_xor(s1, 32);
  if ((lane >> 4) == 0) {
    int cc = c0 + (lane & 15);
    ppart[(size_t)(2 * blockIdx.x) * 128 + cc] = s0;
    ppart[(size_t)(2 * blockIdx.x + 1) * 128 + cc] = s1;
  }
  if (tid == 0) {
    int gl = sbat[63];
    pgid[2 * blockIdx.x] = g0;
    pgid[2 * blockIdx.x + 1] = (gl != g0) ? gl : -1;
  }
}

// ---------------- fused pool-reduce + task head: per (graph,task) row ----------------
__global__ __launch_bounds__(128) void k_pool_head(
    const float* __restrict__ ppart, const int* __restrict__ pgid,
    const int* __restrict__ gstart,
    const float* __restrict__ temb, const int* __restrict__ tasks,
    const float* __restrict__ W0, const float* __restrict__ b0,
    const float* __restrict__ W1, const float* __restrict__ b1,
    const float* __restrict__ W2, const float* __restrict__ b2,
    const float* __restrict__ W3, const float* __restrict__ b3,
    float* __restrict__ out) {
  __shared__ float f[192];
  __shared__ float za[128];
  __shared__ float zb[128];
  int rowi = blockIdx.x, t = threadIdx.x;
  int proto = tasks[rowi*2 + 0];
  int tid2  = tasks[rowi*2 + 1];
  // inline pool2: reduce this graph's block partials
  {
    int blo = gstart[proto] >> 6;
    int bhi = (gstart[proto + 1] - 1) >> 6;
    float acc = 0.f;
    for (int b = blo; b <= bhi; ++b) {
      if (pgid[2 * b] == proto)     acc += ppart[(size_t)(2 * b) * 128 + t];
      if (pgid[2 * b + 1] == proto) acc += ppart[(size_t)(2 * b + 1) * 128 + t];
    }
    float cntf = (float)(gstart[proto + 1] - gstart[proto]);
    f[t] = acc / fmaxf(cntf, 1.f);
  }
  if (t < 64) f[128 + t] = temb[(size_t)tid2*64 + t];
  __syncthreads();
  float a = b0[t];
  for (int k = 0; k < 192; ++k) a += f[k] * W0[k*128 + t];
  za[t] = fmaxf(a, 0.f);
  __syncthreads();
  a = b1[t];
  for (int k = 0; k < 128; ++k) a += za[k] * W1[k*128 + t];
  zb[t] = fmaxf(a, 0.f);
  __syncthreads();
  a = b2[t];
  for (int k = 0; k < 128; ++k) a += zb[k] * W2[k*128 + t];
  za[t] = fmaxf(a, 0.f);
  __syncthreads();
  if (t < 3) {
    a = b3[t];
    for (int k = 0; k < 128; ++k) a += za[k] * W3[k*3 + t];
    out[rowi*3 + t] = a;
  }
}

extern "C" void kernel_launch(void* const* d_in, const int* in_sizes, int n_in,
                              void* d_out, int out_size, void* d_ws, size_t ws_size,
                              hipStream_t stream) {
  const float* h    = (const float*)d_in[0];
  const float* x    = (const float*)d_in[1];
  const int*   ei   = (const int*)d_in[2];
  const int*   batch= (const int*)d_in[4];
  const int*   tasks= (const int*)d_in[5];
  const float* embW = (const float*)d_in[7];
  const float* embB = (const float*)d_in[8];
  const float* resW = (const float*)d_in[9];
  const float* msgW = (const float*)d_in[10];
  const float* msgB = (const float*)d_in[11];
  const float* updW = (const float*)d_in[12];
  const float* updB = (const float*)d_in[13];
  const float* W0 = (const float*)d_in[14]; const float* b0 = (const float*)d_in[15];
  const float* W1 = (const float*)d_in[16]; const float* b1 = (const float*)d_in[17];
  const float* W2 = (const float*)d_in[18]; const float* b2 = (const float*)d_in[19];
  const float* W3 = (const float*)d_in[20]; const float* b3 = (const float*)d_in[21];
  const float* temb = (const float*)d_in[22];
  const int* row = ei;
  const int* col = ei + NE;

  // bf16 buffers first (16B alignment), then fp32, then int2/int
  unsigned short* bws = (unsigned short*)d_ws;
  unsigned short* e0   = bws;  bws += (size_t)NN*128;
  unsigned short* e1   = bws;  bws += (size_t)NN*128;
  unsigned short* A0   = bws;  bws += (size_t)NN*128;
  unsigned short* B0   = bws;  bws += (size_t)NN*128;
  unsigned short* A1   = bws;  bws += (size_t)NN*128;
  unsigned short* B1   = bws;  bws += (size_t)NN*128;
  unsigned short* wbf  = bws;  bws += 10*16384 + 8192;
  float* ws = (float*)bws;
  float* ppart = ws;  ws += (size_t)2*NBLK64*128;
  int2*  spack = (int2*)ws;
  int*   iws   = (int*)(spack + NE);
  int*   cnt    = iws;  iws += NN;
  int*   starts = iws;  iws += NN + 1;
  int*   cursor = iws;  iws += NN;
  int*   gstart = iws;  iws += NB + 1;
  int*   bsum   = iws;  iws += 256;
  int*   pgid   = iws;  iws += 2*NBLK64;

  const unsigned short* embWt = wbf + (size_t)10*16384;

  const unsigned short* m0W1t = wbf + (size_t)0 * 16384;
  const unsigned short* m0W2t = wbf + (size_t)1 * 16384;
  const unsigned short* u0W1t = wbf + (size_t)2 * 16384;
  const unsigned short* u0W2t = wbf + (size_t)3 * 16384;
  const unsigned short* r0Wt  = wbf + (size_t)4 * 16384;
  const unsigned short* m1W1t = wbf + (size_t)5 * 16384;
  const unsigned short* m1W2t = wbf + (size_t)6 * 16384;
  const unsigned short* u1W1t = wbf + (size_t)7 * 16384;
  const unsigned short* u1W2t = wbf + (size_t)8 * 16384;
  const unsigned short* r1Wt  = wbf + (size_t)9 * 16384;

  // 1. zero CSR histogram
  hipMemsetAsync(cnt, 0, NN * sizeof(int), stream);
  // 2. weight prep ∪ CSR histogram + graph starts
  k_prep_count<<<672 + (NE + 255)/256, 256, 0, stream>>>(msgW, updW, resW, embW, wbf,
                                                         col, cnt, batch, gstart);
  // 3-4. scan
  k_scan1<<<SCB, 256, 0, stream>>>(cnt, starts, bsum);
  k_scan3b<<<SCB, 256, 0, stream>>>(starts, bsum, cursor);
  // 5. edge scatter ∪ embed + layer-0 dual msg GEMM
  k_scatter_embed<<<NBLK64 + SCAT_BLK, 512, 0, stream>>>(h, embWt, embB, m0W1t, m0W2t,
                                                         e0, A0, B0, NN,
                                                         row, col, x, cursor, spack);
  // 6. layer 0: fused pull + node update + layer-1 dual GEMM  (A0/B0 -> e1, A1, B1)
  k_node_dual_pull<<<NBLK64, 512, 0, stream>>>(e0, starts, spack, A0, B0,
                                               msgW + 256*128, msgB,
                                               u0W1t, u0W2t, r0Wt, updB,
                                               m1W1t, m1W2t, e1, A1, B1, NN);
  // 7. layer 1: fused pull + node update + pooling partials  (A1/B1 + e1 -> ppart)
  k_node_pool_pull<<<NBLK64, 512, 0, stream>>>(e1, starts, spack, A1, B1,
                                               msgW + (size_t)257*128 + 256*128,
                                               msgB + 128,
                                               u1W1t, u1W2t, r1Wt, updB + 128,
                                               batch, ppart, pgid, NN);
  // 8. pool reduce ∪ task head
  k_pool_head<<<NTROWS, 128, 0, stream>>>(ppart, pgid, gstart, temb, tasks,
                                          W0, b0, W1, b1, W2, b2, W3, b3, (float*)d_out);
}